// Round 1
// 1126.279 us; speedup vs baseline: 1.3881x; 1.3881x over previous
//
#include <hip/hip_runtime.h>

#define B_ 2
#define S_ 2048
#define H_ 4096
#define NH_ 32
#define NKV_ 8
#define HD_ 128
#define QLD 6144   // fused qkv row stride = NH*HD + 2*NKV*HD

typedef __bf16 bf16;
typedef __bf16 bf16x8 __attribute__((ext_vector_type(8)));
typedef __bf16 bf16x4 __attribute__((ext_vector_type(4)));
typedef float floatx4 __attribute__((ext_vector_type(4)));
typedef unsigned int u32;

static __device__ __forceinline__ floatx4 fzero4() {
    floatx4 v; v[0] = 0.f; v[1] = 0.f; v[2] = 0.f; v[3] = 0.f; return v;
}

// async global -> LDS, 16 bytes per lane (wave-uniform base + lane*16)
static __device__ __forceinline__ void gload16(const bf16* g, bf16* l) {
    __builtin_amdgcn_global_load_lds((const __attribute__((address_space(1))) u32*)g,
                                     (__attribute__((address_space(3))) u32*)l,
                                     16, 0, 0);
}

// ---------------------------------------------------------------------------
// fp32 -> bf16 bulk convert (hs staged once; all GEMMs then take bf16 A)
// ---------------------------------------------------------------------------
__global__ void conv_f32_bf16(const float* __restrict__ in, bf16* __restrict__ out) {
    const long long N = (long long)4096 * 4096;
    long long i = ((long long)blockIdx.x * 256 + threadIdx.x) * 8;
    const long long stride = (long long)gridDim.x * 256 * 8;
    for (; i < N; i += stride) {
        float4 a = *(const float4*)(in + i);
        float4 b = *(const float4*)(in + i + 4);
        bf16x8 h;
        h[0] = (bf16)a.x; h[1] = (bf16)a.y; h[2] = (bf16)a.z; h[3] = (bf16)a.w;
        h[4] = (bf16)b.x; h[5] = (bf16)b.y; h[6] = (bf16)b.z; h[7] = (bf16)b.w;
        *(bf16x8*)(out + i) = h;
    }
}

// ---------------------------------------------------------------------------
// m97-structure GEMM: C[M=4096][col0..col0+2048) = A[4096][K=4096] * Bt^T.
// A,B bf16, both staged via global_load_lds (16B), linear LDS, BK=64,
// 128x128 tile, 4 waves, 2 barriers/K-step.  Grid (16,32), XCD-swizzled.
// ---------------------------------------------------------------------------
template <typename TC>
__global__ __launch_bounds__(256) void gemm_bt(const bf16* __restrict__ A,
                                               const bf16* __restrict__ Bt,
                                               TC* __restrict__ C,
                                               int lda, int ldC, int col0) {
    __shared__ __align__(16) bf16 As[128][64];
    __shared__ __align__(16) bf16 Bs[128][64];

    const int tid  = threadIdx.x;
    const int w    = tid >> 6;
    const int lane = tid & 63;
    const int quad = lane >> 4;
    const int l16  = lane & 15;
    const int wr   = (w >> 1) * 64;
    const int wc   = (w & 1) * 64;

    // XCD-aware bijective swizzle: 512 blocks, 512 % 8 == 0
    const int flat = blockIdx.y * 16 + blockIdx.x;
    const int swz  = (flat & 7) * 64 + (flat >> 3);
    const int m0   = (swz >> 4) * 128;
    const int n0   = (swz & 15) * 128;

    floatx4 acc[4][4];
#pragma unroll
    for (int i = 0; i < 4; i++)
#pragma unroll
        for (int j = 0; j < 4; j++) acc[i][j] = fzero4();

    bf16* AsF = &As[0][0];
    bf16* BsF = &Bs[0][0];

    for (int k0 = 0; k0 < 4096; k0 += 64) {
        __syncthreads();   // prior-iteration LDS reads complete
#pragma unroll
        for (int i = 0; i < 4; i++) {
            int g   = i * 256 + tid;          // granule id: row = g>>3, 8 granules/row
            int row = g >> 3;
            int col = (g & 7) << 3;
            gload16(A  + (size_t)(m0 + row) * lda  + k0 + col, AsF + (size_t)g * 8);
            gload16(Bt + (size_t)(n0 + row) * 4096 + k0 + col, BsF + (size_t)g * 8);
        }
        __syncthreads();   // implies s_waitcnt vmcnt(0): staged data visible
#pragma unroll
        for (int ks = 0; ks < 64; ks += 32) {
            bf16x8 af[4], bfg[4];
#pragma unroll
            for (int i = 0; i < 4; i++)
                af[i] = *(const bf16x8*)&As[wr + i * 16 + l16][ks + quad * 8];
#pragma unroll
            for (int j = 0; j < 4; j++)
                bfg[j] = *(const bf16x8*)&Bs[wc + j * 16 + l16][ks + quad * 8];
#pragma unroll
            for (int i = 0; i < 4; i++)
#pragma unroll
                for (int j = 0; j < 4; j++)
                    acc[i][j] = __builtin_amdgcn_mfma_f32_16x16x32_bf16(
                        af[i], bfg[j], acc[i][j], 0, 0, 0);
        }
    }

    // D layout: row = quad*4 + r, col = l16  (m89-verified)
#pragma unroll
    for (int i = 0; i < 4; i++) {
#pragma unroll
        for (int r = 0; r < 4; r++) {
            int row = m0 + wr + i * 16 + quad * 4 + r;
#pragma unroll
            for (int j = 0; j < 4; j++) {
                int col = col0 + n0 + wc + j * 16 + l16;
                C[(size_t)row * ldC + col] = (TC)acc[i][j][r];
            }
        }
    }
}

// ---------------------------------------------------------------------------
// Batched strided transpose + dtype convert: out[z][c][r] = in_base(z)[r][c].
// ---------------------------------------------------------------------------
template <typename TI, typename TO>
__global__ void transpose_b(const TI* __restrict__ in, TO* __restrict__ out,
                            long long irs, long long ors,
                            int zdiv, long long zs1, long long zs2,
                            long long ozs) {
    __shared__ TI t[32][33];
    const int z = blockIdx.z;
    const TI* ip = in + (long long)(z / zdiv) * zs1 + (long long)(z % zdiv) * zs2;
    TO* op = out + (long long)z * ozs;
    const int r0 = blockIdx.y * 32, c0 = blockIdx.x * 32;
    const int tx = threadIdx.x, ty = threadIdx.y;   // block (32,8)
#pragma unroll
    for (int i = 0; i < 4; i++)
        t[ty + i * 8][tx] = ip[(long long)(r0 + ty + i * 8) * irs + c0 + tx];
    __syncthreads();
#pragma unroll
    for (int i = 0; i < 4; i++)
        op[(long long)(c0 + ty + i * 8) * ors + r0 + tx] = (TO)t[tx][ty + i * 8];
}

// ---------------------------------------------------------------------------
// RoPE on q (cols 0..4095 of fused qkv) in place.
// ---------------------------------------------------------------------------
__global__ void rope_q(bf16* __restrict__ q, const float* __restrict__ cosb,
                       const float* __restrict__ sinb) {
    size_t idx = (size_t)blockIdx.x * 256 + threadIdx.x; // B*S*NH*64
    int dp = idx & 63;
    size_t t = idx >> 6;
    int h = (int)(t % NH_);
    size_t bs = t / NH_;                 // b*S + s
    size_t base = bs * QLD + (size_t)h * HD_;
    float x1 = (float)q[base + dp];
    float x2 = (float)q[base + dp + 64];
    float c1 = cosb[bs * HD_ + dp];
    float s1 = sinb[bs * HD_ + dp];
    float c2 = cosb[bs * HD_ + dp + 64];
    float s2 = sinb[bs * HD_ + dp + 64];
    q[base + dp]      = (bf16)(x1 * c1 - x2 * s1);
    q[base + dp + 64] = (bf16)(x2 * c2 + x1 * s2);
}

// ---------------------------------------------------------------------------
// RoPE + repack K:  qkv cols [4096,5120)  ->  kout [b][kv][s][d]   (bf16)
// ---------------------------------------------------------------------------
__global__ void repack_k_rope(const bf16* __restrict__ qkv, bf16* __restrict__ kout,
                              const float* __restrict__ cosb,
                              const float* __restrict__ sinb) {
    size_t idx = (size_t)blockIdx.x * 256 + threadIdx.x; // B*S*NKV*64
    int dp = idx & 63;
    size_t t = idx >> 6;
    int kv = (int)(t % NKV_);
    size_t bs = t / NKV_;                // b*S + s
    int b = (int)(bs / S_);
    int s = (int)(bs % S_);
    size_t ibase = bs * QLD + (size_t)(NH_ * HD_) + (size_t)kv * HD_;
    float x1 = (float)qkv[ibase + dp];
    float x2 = (float)qkv[ibase + dp + 64];
    float c1 = cosb[bs * HD_ + dp];
    float s1 = sinb[bs * HD_ + dp];
    float c2 = cosb[bs * HD_ + dp + 64];
    float s2 = sinb[bs * HD_ + dp + 64];
    size_t obase = (((size_t)b * NKV_ + kv) * S_ + s) * HD_;
    kout[obase + dp]      = (bf16)(x1 * c1 - x2 * s1);
    kout[obase + dp + 64] = (bf16)(x2 * c2 + x1 * s2);
}

// ---------------------------------------------------------------------------
// Causal flash attention, IN PLACE (O overwrites Q inside fused qkv).
// Q/O rows stride QLD; Kp [b][kv][s][d]; Vt [b][kv][d][s].
// Changes vs prev round: Q staged through Ks (LDS 62.5->44 KB => 3 blk/CU),
// next K/V tile register-prefetched before compute, Ps barrier dropped
// (per-wave buffer; intra-wave LDS ordering is architectural).
// ---------------------------------------------------------------------------
__global__ __launch_bounds__(256) void flash_fwd(const bf16* Q,
                                                 const bf16* __restrict__ Kp,
                                                 const bf16* __restrict__ Vt,
                                                 bf16* O) {
    __shared__ __align__(16) bf16 Ks[64][136];
    __shared__ __align__(16) bf16 Vs[128][72];
    __shared__ __align__(16) bf16 Ps[4][16][72];

    const float scale = 0.08838834764831845f;  // 1/sqrt(128)
    const int qb = blockIdx.x, bh = blockIdx.y;
    const int b = bh / NH_, h = bh % NH_, kv = h >> 2;  // NH/NKV = 4
    const int q0 = qb * 64;
    const int tid = threadIdx.x, w = tid >> 6, lane = tid & 63;
    const int quad = lane >> 4, l16 = lane & 15;

    const bf16* Qb = Q + (size_t)b * S_ * QLD + (size_t)h * HD_;
    const bf16* Kb = Kp + ((size_t)(b * NKV_ + kv)) * S_ * HD_;
    const bf16* Vb = Vt + ((size_t)(b * NKV_ + kv)) * (size_t)HD_ * S_;

    // stage Q tile (64 x 128) through Ks, pull into registers
#pragma unroll
    for (int i = 0; i < 4; i++) {
        int vec = tid + 256 * i;
        int row = vec >> 4, col = (vec & 15) << 3;
        *(bf16x8*)&Ks[row][col] =
            *(const bf16x8*)(Qb + (size_t)(q0 + row) * QLD + col);
    }
    __syncthreads();
    bf16x8 qf[4];
#pragma unroll
    for (int ks = 0; ks < 4; ks++)
        qf[ks] = *(const bf16x8*)&Ks[w * 16 + l16][ks * 32 + quad * 8];

    floatx4 of[8];
#pragma unroll
    for (int n = 0; n < 8; n++) of[n] = fzero4();
    float mi[4], li[4];
#pragma unroll
    for (int r = 0; r < 4; r++) { mi[r] = -1e30f; li[r] = 0.f; }

    // prefetch tile 0 into registers
    bf16x8 kreg[4], vreg[4];
#pragma unroll
    for (int i = 0; i < 4; i++) {
        int vec = tid + 256 * i;
        kreg[i] = *(const bf16x8*)(Kb + (size_t)(vec >> 4) * HD_ + ((vec & 15) << 3));
        vreg[i] = *(const bf16x8*)(Vb + (size_t)(vec >> 3) * S_ + ((vec & 7) << 3));
    }

    const int nT = qb + 1;
    for (int j = 0; j < nT; ++j) {
        const int kbase = j * 64;
        __syncthreads();   // everyone done reading Ks/Vs (and Q at j=0)
#pragma unroll
        for (int i = 0; i < 4; i++) {
            int vec = tid + 256 * i;
            *(bf16x8*)&Ks[vec >> 4][(vec & 15) << 3] = kreg[i];
            *(bf16x8*)&Vs[vec >> 3][(vec & 7) << 3] = vreg[i];
        }
        __syncthreads();   // staged tile visible

        // issue next tile's global loads; latency hides under compute below
        if (j + 1 < nT) {
            const int kn = kbase + 64;
#pragma unroll
            for (int i = 0; i < 4; i++) {
                int vec = tid + 256 * i;
                kreg[i] = *(const bf16x8*)(Kb + (size_t)(kn + (vec >> 4)) * HD_ + ((vec & 15) << 3));
                vreg[i] = *(const bf16x8*)(Vb + (size_t)(vec >> 3) * S_ + kn + ((vec & 7) << 3));
            }
        }

        // scores: 16 q-rows x 64 keys per wave
        floatx4 sa[4];
#pragma unroll
        for (int n = 0; n < 4; n++) sa[n] = fzero4();
#pragma unroll
        for (int ks = 0; ks < 4; ks++) {
#pragma unroll
            for (int n = 0; n < 4; n++) {
                bf16x8 kf = *(const bf16x8*)&Ks[n * 16 + l16][ks * 32 + quad * 8];
                sa[n] = __builtin_amdgcn_mfma_f32_16x16x32_bf16(qf[ks], kf, sa[n], 0, 0, 0);
            }
        }

        const bool diag = (j == qb);
#pragma unroll
        for (int n = 0; n < 4; n++)
#pragma unroll
            for (int r = 0; r < 4; r++) {
                float s = sa[n][r] * scale;
                if (diag) {
                    int row = q0 + w * 16 + quad * 4 + r;
                    int col = kbase + n * 16 + l16;
                    if (col > row) s = -1e30f;
                }
                sa[n][r] = s;
            }

        // row max (16 lanes of a quad hold one row; butterfly over l16 bits)
        float al[4];
#pragma unroll
        for (int r = 0; r < 4; r++) {
            float m = sa[0][r];
#pragma unroll
            for (int n = 1; n < 4; n++) m = fmaxf(m, sa[n][r]);
            m = fmaxf(m, __shfl_xor(m, 1));
            m = fmaxf(m, __shfl_xor(m, 2));
            m = fmaxf(m, __shfl_xor(m, 4));
            m = fmaxf(m, __shfl_xor(m, 8));
            float mn = fmaxf(mi[r], m);
            al[r] = __expf(mi[r] - mn);
            mi[r] = mn;
        }

        float ls[4] = {0.f, 0.f, 0.f, 0.f};
#pragma unroll
        for (int n = 0; n < 4; n++)
#pragma unroll
            for (int r = 0; r < 4; r++) {
                float p = __expf(sa[n][r] - mi[r]);
                sa[n][r] = p;
                ls[r] += p;
            }
#pragma unroll
        for (int r = 0; r < 4; r++) {
            float s = ls[r];
            s += __shfl_xor(s, 1);
            s += __shfl_xor(s, 2);
            s += __shfl_xor(s, 4);
            s += __shfl_xor(s, 8);
            li[r] = li[r] * al[r] + s;
        }

        // P: D-layout -> per-wave LDS slab -> A-operand layout (no barrier:
        // same-wave LDS write->read is in-order)
#pragma unroll
        for (int n = 0; n < 4; n++)
#pragma unroll
            for (int r = 0; r < 4; r++)
                Ps[w][quad * 4 + r][n * 16 + l16] = (bf16)sa[n][r];

        // rescale O
#pragma unroll
        for (int n = 0; n < 8; n++)
#pragma unroll
            for (int r = 0; r < 4; r++) of[n][r] *= al[r];

        // PV: P (16x64) x V (64x128)
#pragma unroll
        for (int ks = 0; ks < 2; ks++) {
            bf16x8 ap = *(const bf16x8*)&Ps[w][l16][ks * 32 + quad * 8];
#pragma unroll
            for (int n = 0; n < 8; n++) {
                bf16x8 vf = *(const bf16x8*)&Vs[n * 16 + l16][ks * 32 + quad * 8];
                of[n] = __builtin_amdgcn_mfma_f32_16x16x32_bf16(ap, vf, of[n], 0, 0, 0);
            }
        }
    }

    // epilogue: O /= l, write back in place over Q (stride QLD)
#pragma unroll
    for (int r = 0; r < 4; r++) {
        float inv = 1.f / li[r];
        int srow = q0 + w * 16 + quad * 4 + r;
        size_t base = ((size_t)b * S_ + srow) * QLD + (size_t)h * HD_;
        bf16* Ob = O + base;
#pragma unroll
        for (int n = 0; n < 8; n++)
            Ob[n * 16 + l16] = (bf16)(of[n][r] * inv);
    }
}

// ---------------------------------------------------------------------------
extern "C" void kernel_launch(void* const* d_in, const int* in_sizes, int n_in,
                              void* d_out, int out_size, void* d_ws, size_t ws_size,
                              hipStream_t stream) {
    const float* hs   = (const float*)d_in[0];
    const float* cosb = (const float*)d_in[1];
    const float* sinb = (const float*)d_in[2];
    const float* wq   = (const float*)d_in[3];
    const float* wk   = (const float*)d_in[4];
    const float* wv   = (const float*)d_in[5];
    const float* wo   = (const float*)d_in[6];
    float* out = (float*)d_out;
    (void)in_sizes; (void)n_in; (void)out_size;

    // 64 MiB workspace (< proven-available 72 MiB)
    const size_t NEED = (size_t)64 * 1024 * 1024;
    if (ws_size < NEED) return;

    char* ws = (char*)d_ws;
    bf16* qkv = (bf16*)ws;                                   // 48 MiB: [4096][6144]
    bf16* R1  = (bf16*)(ws + (size_t)48 * 1024 * 1024);      // 16 MiB shared region

    // hs -> bf16, stashed in d_out (dead before wo-GEMM writes d_out)
    bf16* hsb = (bf16*)d_out;                                // 32 of 64 MiB

    dim3 tb(32, 8, 1);

    conv_f32_bf16<<<2048, 256, 0, stream>>>(hs, hsb);

    // Q projection: 2 strips of 2048 cols (strip = 16 MiB in R1)
    for (int s = 0; s < 2; s++) {
        transpose_b<float, bf16><<<dim3(64, 128, 1), tb, 0, stream>>>(
            wq + 2048 * s, R1, 4096, 4096, 1, 0, 0, 0);
        gemm_bt<bf16><<<dim3(16, 32), 256, 0, stream>>>(
            hsb, R1, qkv, 4096, QLD, 2048 * s);
    }
    // K+V fused: wk^T -> R1 rows [0,1024), wv^T -> rows [1024,2048)
    transpose_b<float, bf16><<<dim3(32, 128, 1), tb, 0, stream>>>(
        wk, R1, 1024, 4096, 1, 0, 0, 0);
    transpose_b<float, bf16><<<dim3(32, 128, 1), tb, 0, stream>>>(
        wv, R1 + (size_t)1024 * 4096, 1024, 4096, 1, 0, 0, 0);
    gemm_bt<bf16><<<dim3(16, 32), 256, 0, stream>>>(
        hsb, R1, qkv, 4096, QLD, 4096);

    // rope q in place; repack K (rope) and transpose V out of qkv
    rope_q<<<(B_ * S_ * NH_ * 64) / 256, 256, 0, stream>>>(qkv, cosb, sinb);
    bf16* Kpk = R1;                                          // 8 MiB
    bf16* Vtv = R1 + (size_t)B_ * NKV_ * S_ * HD_;           // 8 MiB
    repack_k_rope<<<(B_ * S_ * NKV_ * 64) / 256, 256, 0, stream>>>(
        qkv, Kpk, cosb, sinb);
    // V: qkv cols [5120,6144) [b][s][kv][d] -> [b*kv][d][s]
    transpose_b<bf16, bf16><<<dim3(HD_ / 32, S_ / 32, B_ * NKV_), tb, 0, stream>>>(
        qkv + NH_ * HD_ + NKV_ * HD_, Vtv, QLD, S_,
        NKV_, (long long)S_ * QLD, HD_, (long long)HD_ * S_);

    // attention (in place over q columns of qkv)
    flash_fwd<<<dim3(S_ / 64, B_ * NH_), 256, 0, stream>>>(qkv, Kpk, Vtv, qkv);

    // output projection: 2 strips of 2048 cols, fp32 out (overwrites hsb)
    for (int s = 0; s < 2; s++) {
        transpose_b<float, bf16><<<dim3(64, 128, 1), tb, 0, stream>>>(
            wo + 2048 * s, R1, 4096, 4096, 1, 0, 0, 0);
        gemm_bt<float><<<dim3(16, 32), 256, 0, stream>>>(
            qkv, R1, out, QLD, 4096, 2048 * s);
    }
}

// Round 2
// 1085.133 us; speedup vs baseline: 1.4408x; 1.0379x over previous
//
#include <hip/hip_runtime.h>

#define B_ 2
#define S_ 2048
#define H_ 4096
#define NH_ 32
#define NKV_ 8
#define HD_ 128
#define QLD 6144   // fused qkv row stride = NH*HD + 2*NKV*HD

typedef __bf16 bf16;
typedef __bf16 bf16x8 __attribute__((ext_vector_type(8)));
typedef __bf16 bf16x4 __attribute__((ext_vector_type(4)));
typedef float floatx4 __attribute__((ext_vector_type(4)));
typedef float floatx16 __attribute__((ext_vector_type(16)));
typedef unsigned int u32;

static __device__ __forceinline__ floatx4 fzero4() {
    floatx4 v; v[0] = 0.f; v[1] = 0.f; v[2] = 0.f; v[3] = 0.f; return v;
}

// async global -> LDS, 16 bytes per lane (dest linear in lane; src per-lane)
static __device__ __forceinline__ void gload16(const bf16* g, bf16* l) {
    __builtin_amdgcn_global_load_lds((const __attribute__((address_space(1))) u32*)g,
                                     (__attribute__((address_space(3))) u32*)l,
                                     16, 0, 0);
}

// ---------------------------------------------------------------------------
// fp32 -> bf16 bulk convert (hs staged once; all GEMMs then take bf16 A)
// ---------------------------------------------------------------------------
__global__ void conv_f32_bf16(const float* __restrict__ in, bf16* __restrict__ out) {
    const long long N = (long long)4096 * 4096;
    long long i = ((long long)blockIdx.x * 256 + threadIdx.x) * 8;
    const long long stride = (long long)gridDim.x * 256 * 8;
    for (; i < N; i += stride) {
        float4 a = *(const float4*)(in + i);
        float4 b = *(const float4*)(in + i + 4);
        bf16x8 h;
        h[0] = (bf16)a.x; h[1] = (bf16)a.y; h[2] = (bf16)a.z; h[3] = (bf16)a.w;
        h[4] = (bf16)b.x; h[5] = (bf16)b.y; h[6] = (bf16)b.z; h[7] = (bf16)b.w;
        *(bf16x8*)(out + i) = h;
    }
}

// ---------------------------------------------------------------------------
// m97-structure GEMM: C[M=4096][col0..col0+2048) = A[4096][K=4096] * Bt^T.
// ---------------------------------------------------------------------------
template <typename TC>
__global__ __launch_bounds__(256) void gemm_bt(const bf16* __restrict__ A,
                                               const bf16* __restrict__ Bt,
                                               TC* __restrict__ C,
                                               int lda, int ldC, int col0) {
    __shared__ __align__(16) bf16 As[128][64];
    __shared__ __align__(16) bf16 Bs[128][64];

    const int tid  = threadIdx.x;
    const int w    = tid >> 6;
    const int lane = tid & 63;
    const int quad = lane >> 4;
    const int l16  = lane & 15;
    const int wr   = (w >> 1) * 64;
    const int wc   = (w & 1) * 64;

    const int flat = blockIdx.y * 16 + blockIdx.x;
    const int swz  = (flat & 7) * 64 + (flat >> 3);
    const int m0   = (swz >> 4) * 128;
    const int n0   = (swz & 15) * 128;

    floatx4 acc[4][4];
#pragma unroll
    for (int i = 0; i < 4; i++)
#pragma unroll
        for (int j = 0; j < 4; j++) acc[i][j] = fzero4();

    bf16* AsF = &As[0][0];
    bf16* BsF = &Bs[0][0];

    for (int k0 = 0; k0 < 4096; k0 += 64) {
        __syncthreads();
#pragma unroll
        for (int i = 0; i < 4; i++) {
            int g   = i * 256 + tid;
            int row = g >> 3;
            int col = (g & 7) << 3;
            gload16(A  + (size_t)(m0 + row) * lda  + k0 + col, AsF + (size_t)g * 8);
            gload16(Bt + (size_t)(n0 + row) * 4096 + k0 + col, BsF + (size_t)g * 8);
        }
        __syncthreads();
#pragma unroll
        for (int ks = 0; ks < 64; ks += 32) {
            bf16x8 af[4], bfg[4];
#pragma unroll
            for (int i = 0; i < 4; i++)
                af[i] = *(const bf16x8*)&As[wr + i * 16 + l16][ks + quad * 8];
#pragma unroll
            for (int j = 0; j < 4; j++)
                bfg[j] = *(const bf16x8*)&Bs[wc + j * 16 + l16][ks + quad * 8];
#pragma unroll
            for (int i = 0; i < 4; i++)
#pragma unroll
                for (int j = 0; j < 4; j++)
                    acc[i][j] = __builtin_amdgcn_mfma_f32_16x16x32_bf16(
                        af[i], bfg[j], acc[i][j], 0, 0, 0);
        }
    }

#pragma unroll
    for (int i = 0; i < 4; i++) {
#pragma unroll
        for (int r = 0; r < 4; r++) {
            int row = m0 + wr + i * 16 + quad * 4 + r;
#pragma unroll
            for (int j = 0; j < 4; j++) {
                int col = col0 + n0 + wc + j * 16 + l16;
                C[(size_t)row * ldC + col] = (TC)acc[i][j][r];
            }
        }
    }
}

// ---------------------------------------------------------------------------
// Batched strided transpose + dtype convert: out[z][c][r] = in_base(z)[r][c].
// ---------------------------------------------------------------------------
template <typename TI, typename TO>
__global__ void transpose_b(const TI* __restrict__ in, TO* __restrict__ out,
                            long long irs, long long ors,
                            int zdiv, long long zs1, long long zs2,
                            long long ozs) {
    __shared__ TI t[32][33];
    const int z = blockIdx.z;
    const TI* ip = in + (long long)(z / zdiv) * zs1 + (long long)(z % zdiv) * zs2;
    TO* op = out + (long long)z * ozs;
    const int r0 = blockIdx.y * 32, c0 = blockIdx.x * 32;
    const int tx = threadIdx.x, ty = threadIdx.y;   // block (32,8)
#pragma unroll
    for (int i = 0; i < 4; i++)
        t[ty + i * 8][tx] = ip[(long long)(r0 + ty + i * 8) * irs + c0 + tx];
    __syncthreads();
#pragma unroll
    for (int i = 0; i < 4; i++)
        op[(long long)(c0 + ty + i * 8) * ors + r0 + tx] = (TO)t[tx][ty + i * 8];
}

// ---------------------------------------------------------------------------
// RoPE on q (cols 0..4095 of fused qkv) in place.
// ---------------------------------------------------------------------------
__global__ void rope_q(bf16* __restrict__ q, const float* __restrict__ cosb,
                       const float* __restrict__ sinb) {
    size_t idx = (size_t)blockIdx.x * 256 + threadIdx.x; // B*S*NH*64
    int dp = idx & 63;
    size_t t = idx >> 6;
    int h = (int)(t % NH_);
    size_t bs = t / NH_;                 // b*S + s
    size_t base = bs * QLD + (size_t)h * HD_;
    float x1 = (float)q[base + dp];
    float x2 = (float)q[base + dp + 64];
    float c1 = cosb[bs * HD_ + dp];
    float s1 = sinb[bs * HD_ + dp];
    float c2 = cosb[bs * HD_ + dp + 64];
    float s2 = sinb[bs * HD_ + dp + 64];
    q[base + dp]      = (bf16)(x1 * c1 - x2 * s1);
    q[base + dp + 64] = (bf16)(x2 * c2 + x1 * s2);
}

// ---------------------------------------------------------------------------
// RoPE + repack K:  qkv cols [4096,5120)  ->  kout [b][kv][s][d]   (bf16)
// ---------------------------------------------------------------------------
__global__ void repack_k_rope(const bf16* __restrict__ qkv, bf16* __restrict__ kout,
                              const float* __restrict__ cosb,
                              const float* __restrict__ sinb) {
    size_t idx = (size_t)blockIdx.x * 256 + threadIdx.x; // B*S*NKV*64
    int dp = idx & 63;
    size_t t = idx >> 6;
    int kv = (int)(t % NKV_);
    size_t bs = t / NKV_;                // b*S + s
    int b = (int)(bs / S_);
    int s = (int)(bs % S_);
    size_t ibase = bs * QLD + (size_t)(NH_ * HD_) + (size_t)kv * HD_;
    float x1 = (float)qkv[ibase + dp];
    float x2 = (float)qkv[ibase + dp + 64];
    float c1 = cosb[bs * HD_ + dp];
    float s1 = sinb[bs * HD_ + dp];
    float c2 = cosb[bs * HD_ + dp + 64];
    float s2 = sinb[bs * HD_ + dp + 64];
    size_t obase = (((size_t)b * NKV_ + kv) * S_ + s) * HD_;
    kout[obase + dp]      = (bf16)(x1 * c1 - x2 * s1);
    kout[obase + dp + 64] = (bf16)(x2 * c2 + x1 * s2);
}

// ---------------------------------------------------------------------------
// Causal flash attention v2: 32x32x16 MFMA, swapped QK^T (S^T = K*Q^T) so
// softmax is lane-local; P repacked in-register (shfl_xor 32); K/V staged via
// global_load_lds with pre-swizzled source + XOR-swizzled reads (rule #21).
// QBLK=128 (4 waves x 32 q-rows), KVBLK=64.  IN PLACE: O overwrites Q cols.
// ---------------------------------------------------------------------------
__global__ __launch_bounds__(256) void flash_fwd(const bf16* __restrict__ Q,
                                                 const bf16* __restrict__ Kp,
                                                 const bf16* __restrict__ Vt,
                                                 bf16* __restrict__ O) {
    __shared__ __align__(16) bf16 smem[17408];   // 34816 B
    bf16* Ks = smem;            // [64][128] els, granule ^= (row&15), 16 KB
    bf16* Vs = smem + 8192;     // [128][64] els, 256B super-rows, 16 KB

    const float scale = 0.08838834764831845f;  // 1/sqrt(128)
    const int qb = blockIdx.x, bh = blockIdx.y;
    const int b = bh >> 5, h = bh & 31, kv = h >> 2;   // NH=32, NH/NKV=4
    const int q0 = qb * 128;
    const int tid = threadIdx.x, w = tid >> 6, lane = tid & 63;
    const int l32 = lane & 31, hlf = lane >> 5;

    const bf16* Qb = Q + (size_t)b * S_ * QLD + (size_t)h * HD_;
    const bf16* Kb = Kp + (size_t)(b * NKV_ + kv) * S_ * HD_;
    const bf16* Vb = Vt + (size_t)(b * NKV_ + kv) * (size_t)HD_ * S_;

    // Q fragment (B-operand: lane holds col q=l32, k-rows hlf*8..+8 per step)
    const int qrow = q0 + w * 32 + l32;
    const bf16* Qr = Qb + (size_t)qrow * QLD;
    bf16x8 qf[8];
#pragma unroll
    for (int ks = 0; ks < 8; ks++)
        qf[ks] = *(const bf16x8*)(Qr + ks * 16 + hlf * 8);

    floatx16 ot[4];   // O^T: lane holds 16 d-values (32x32 C-layout) for its q
#pragma unroll
    for (int dt = 0; dt < 4; dt++)
#pragma unroll
        for (int r = 0; r < 16; r++) ot[dt][r] = 0.f;
    float mi = -1e30f, li = 0.f;

    const int wqmax = q0 + w * 32 + 31;
    const int nT = 2 * qb + 2;

    for (int j = 0; j < nT; ++j) {
        const int kbase = j * 64;
        __syncthreads();   // prior-iter LDS reads done
        // K tile 64x128: 16 granules/row; dest linear, src granule ^= (row&15)
#pragma unroll
        for (int i = 0; i < 4; i++) {
            int G = i * 256 + tid;
            int r = G >> 4, gp = G & 15;
            int gl = gp ^ (r & 15);
            gload16(Kb + (size_t)(kbase + r) * HD_ + gl * 8, Ks + (size_t)G * 8);
        }
        // V tile 128x64: 2 d-rows = one 256B super-row of 16 granules
#pragma unroll
        for (int i = 0; i < 4; i++) {
            int G = i * 256 + tid;
            int R = G >> 4, gp = G & 15;
            int g16 = gp ^ (R & 15);
            int d = R * 2 + (g16 >> 3);
            int kg = g16 & 7;
            gload16(Vb + (size_t)d * S_ + kbase + kg * 8, Vs + (size_t)G * 8);
        }
        __syncthreads();   // drains vmcnt: staged tile visible

        if (kbase <= wqmax) {   // wave-uniform; skip fully-masked tiles
            // S^T = K * Q^T : two 32-key x 32-q tiles
            floatx16 st[2];
#pragma unroll
            for (int n = 0; n < 2; n++)
#pragma unroll
                for (int r = 0; r < 16; r++) st[n][r] = 0.f;
#pragma unroll
            for (int ks = 0; ks < 8; ks++) {
#pragma unroll
                for (int n = 0; n < 2; n++) {
                    int rr = n * 32 + l32;
                    int phys = (ks * 2 + hlf) ^ (l32 & 15);
                    bf16x8 kf = *(const bf16x8*)(Ks + (size_t)rr * 128 + phys * 8);
                    st[n] = __builtin_amdgcn_mfma_f32_32x32x16_bf16(
                        kf, qf[ks], st[n], 0, 0, 0);
                }
            }
            // scale + causal mask (key from 32x32 C row pattern)
#pragma unroll
            for (int n = 0; n < 2; n++)
#pragma unroll
                for (int r = 0; r < 16; r++) {
                    float s = st[n][r] * scale;
                    int key = kbase + n * 32 + (r & 3) + 8 * (r >> 2) + 4 * hlf;
                    st[n][r] = (key > qrow) ? -1e30f : s;
                }
            // lane-local softmax; combine halves with one shfl_xor(32)
            float m = st[0][0];
#pragma unroll
            for (int r = 1; r < 16; r++) m = fmaxf(m, st[0][r]);
#pragma unroll
            for (int r = 0; r < 16; r++) m = fmaxf(m, st[1][r]);
            m = fmaxf(m, __shfl_xor(m, 32));
            float mn = fmaxf(mi, m);
            float al = __expf(mi - mn);
            mi = mn;
            float ls = 0.f;
#pragma unroll
            for (int n = 0; n < 2; n++)
#pragma unroll
                for (int r = 0; r < 16; r++) {
                    float p = __expf(st[n][r] - mi);
                    st[n][r] = p;
                    ls += p;
                }
            ls += __shfl_xor(ls, 32);
            li = li * al + ls;

            // repack P -> PV B-frags: lane needs 8 consecutive keys; swap
            // 4 values with lane^32 per 16-key slice (T12 mechanism)
            bf16x8 pb[4];
#pragma unroll
            for (int ks2 = 0; ks2 < 4; ks2++) {
                const int n = ks2 >> 1;
                const int rb = (ks2 & 1) * 8;
                float s0 = hlf ? st[n][rb + 0] : st[n][rb + 4];
                float s1 = hlf ? st[n][rb + 1] : st[n][rb + 5];
                float s2 = hlf ? st[n][rb + 2] : st[n][rb + 6];
                float s3 = hlf ? st[n][rb + 3] : st[n][rb + 7];
                float r0 = __shfl_xor(s0, 32);
                float r1 = __shfl_xor(s1, 32);
                float r2 = __shfl_xor(s2, 32);
                float r3 = __shfl_xor(s3, 32);
                float e0, e1, e2, e3, e4, e5, e6, e7;
                if (hlf == 0) {
                    e0 = st[n][rb + 0]; e1 = st[n][rb + 1];
                    e2 = st[n][rb + 2]; e3 = st[n][rb + 3];
                    e4 = r0; e5 = r1; e6 = r2; e7 = r3;
                } else {
                    e0 = r0; e1 = r1; e2 = r2; e3 = r3;
                    e4 = st[n][rb + 4]; e5 = st[n][rb + 5];
                    e6 = st[n][rb + 6]; e7 = st[n][rb + 7];
                }
                bf16x8 t;
                t[0] = (bf16)e0; t[1] = (bf16)e1; t[2] = (bf16)e2; t[3] = (bf16)e3;
                t[4] = (bf16)e4; t[5] = (bf16)e5; t[6] = (bf16)e6; t[7] = (bf16)e7;
                pb[ks2] = t;
            }

            // rescale O^T, then PV: O^T[d][q] += V^T[d][k] * P^T[k][q]
#pragma unroll
            for (int dt = 0; dt < 4; dt++)
#pragma unroll
                for (int r = 0; r < 16; r++) ot[dt][r] *= al;
#pragma unroll
            for (int ks2 = 0; ks2 < 4; ks2++) {
#pragma unroll
                for (int dt = 0; dt < 4; dt++) {
                    int d = dt * 32 + l32;
                    int g16 = ((d & 1) * 8 + ks2 * 2 + hlf) ^ ((d >> 1) & 15);
                    bf16x8 vf = *(const bf16x8*)(Vs + (size_t)(d >> 1) * 128 + g16 * 8);
                    ot[dt] = __builtin_amdgcn_mfma_f32_32x32x16_bf16(
                        vf, pb[ks2], ot[dt], 0, 0, 0);
                }
            }
        }
    }

    // epilogue: O^T regs -> LDS (row-major per q) -> coalesced global store
    __syncthreads();   // all waves done with Ks/Vs
    {
        const float inv = 1.f / li;
        bf16* Os = smem + (size_t)w * 32 * 136;   // stride 136 els = 272 B
#pragma unroll
        for (int dt = 0; dt < 4; dt++)
#pragma unroll
            for (int r = 0; r < 16; r++) {
                int d = dt * 32 + (r & 3) + 8 * (r >> 2) + 4 * hlf;
                Os[l32 * 136 + d] = (bf16)(ot[dt][r] * inv);
            }
    }
    __syncthreads();
    {
        bf16* Ob = O + (size_t)b * S_ * QLD + (size_t)h * HD_;
#pragma unroll
        for (int i = 0; i < 8; i++) {
            int u = i * 256 + tid;
            int qa = u >> 4, gr = u & 15;
            bf16x8 v = *(const bf16x8*)(smem + (size_t)qa * 136 + gr * 8);
            *(bf16x8*)(Ob + (size_t)(q0 + qa) * QLD + gr * 8) = v;
        }
    }
}

// ---------------------------------------------------------------------------
extern "C" void kernel_launch(void* const* d_in, const int* in_sizes, int n_in,
                              void* d_out, int out_size, void* d_ws, size_t ws_size,
                              hipStream_t stream) {
    const float* hs   = (const float*)d_in[0];
    const float* cosb = (const float*)d_in[1];
    const float* sinb = (const float*)d_in[2];
    const float* wq   = (const float*)d_in[3];
    const float* wk   = (const float*)d_in[4];
    const float* wv   = (const float*)d_in[5];
    const float* wo   = (const float*)d_in[6];
    float* out = (float*)d_out;
    (void)in_sizes; (void)n_in; (void)out_size;

    const size_t NEED = (size_t)64 * 1024 * 1024;
    if (ws_size < NEED) return;

    char* ws = (char*)d_ws;
    bf16* qkv = (bf16*)ws;                                   // 48 MiB: [4096][6144]
    bf16* R1  = (bf16*)(ws + (size_t)48 * 1024 * 1024);      // 16 MiB shared region

    bf16* hsb = (bf16*)d_out;                                // 32 of 64 MiB

    dim3 tb(32, 8, 1);

    conv_f32_bf16<<<2048, 256, 0, stream>>>(hs, hsb);

    // Q projection: 2 strips of 2048 cols (strip = 16 MiB in R1)
    for (int s = 0; s < 2; s++) {
        transpose_b<float, bf16><<<dim3(64, 128, 1), tb, 0, stream>>>(
            wq + 2048 * s, R1, 4096, 4096, 1, 0, 0, 0);
        gemm_bt<bf16><<<dim3(16, 32), 256, 0, stream>>>(
            hsb, R1, qkv, 4096, QLD, 2048 * s);
    }
    // K+V fused: wk^T -> R1 rows [0,1024), wv^T -> rows [1024,2048)
    transpose_b<float, bf16><<<dim3(32, 128, 1), tb, 0, stream>>>(
        wk, R1, 1024, 4096, 1, 0, 0, 0);
    transpose_b<float, bf16><<<dim3(32, 128, 1), tb, 0, stream>>>(
        wv, R1 + (size_t)1024 * 4096, 1024, 4096, 1, 0, 0, 0);
    gemm_bt<bf16><<<dim3(16, 32), 256, 0, stream>>>(
        hsb, R1, qkv, 4096, QLD, 4096);

    // rope q in place; repack K (rope) and transpose V out of qkv
    rope_q<<<(B_ * S_ * NH_ * 64) / 256, 256, 0, stream>>>(qkv, cosb, sinb);
    bf16* Kpk = R1;                                          // 8 MiB
    bf16* Vtv = R1 + (size_t)B_ * NKV_ * S_ * HD_;           // 8 MiB
    repack_k_rope<<<(B_ * S_ * NKV_ * 64) / 256, 256, 0, stream>>>(
        qkv, Kpk, cosb, sinb);
    // V: qkv cols [5120,6144) [b][s][kv][d] -> [b*kv][d][s]
    transpose_b<bf16, bf16><<<dim3(HD_ / 32, S_ / 32, B_ * NKV_), tb, 0, stream>>>(
        qkv + NH_ * HD_ + NKV_ * HD_, Vtv, QLD, S_,
        NKV_, (long long)S_ * QLD, HD_, (long long)HD_ * S_);

    // attention v2: QBLK=128 blocks
    flash_fwd<<<dim3(S_ / 128, B_ * NH_), 256, 0, stream>>>(qkv, Kpk, Vtv, qkv);

    // output projection: 2 strips of 2048 cols, fp32 out (overwrites hsb)
    for (int s = 0; s < 2; s++) {
        transpose_b<float, bf16><<<dim3(64, 128, 1), tb, 0, stream>>>(
            wo + 2048 * s, R1, 4096, 4096, 1, 0, 0, 0);
        gemm_bt<float><<<dim3(16, 32), 256, 0, stream>>>(
            qkv, R1, out, QLD, 4096, 2048 * s);
    }
}

// Round 3
// 1005.115 us; speedup vs baseline: 1.5555x; 1.0796x over previous
//
#include <hip/hip_runtime.h>

#define B_ 2
#define S_ 2048
#define H_ 4096
#define NH_ 32
#define NKV_ 8
#define HD_ 128
#define QLD 6144   // fused qkv row stride = NH*HD + 2*NKV*HD

typedef __bf16 bf16;
typedef __bf16 bf16x8 __attribute__((ext_vector_type(8)));
typedef float floatx4 __attribute__((ext_vector_type(4)));
typedef float floatx16 __attribute__((ext_vector_type(16)));
typedef unsigned int u32;

static __device__ __forceinline__ floatx4 fzero4() {
    floatx4 v; v[0] = 0.f; v[1] = 0.f; v[2] = 0.f; v[3] = 0.f; return v;
}

// async global -> LDS, 16 bytes per lane (dest linear in lane; src per-lane)
static __device__ __forceinline__ void gload16(const bf16* g, bf16* l) {
    __builtin_amdgcn_global_load_lds((const __attribute__((address_space(1))) u32*)g,
                                     (__attribute__((address_space(3))) u32*)l,
                                     16, 0, 0);
}

// ---------------------------------------------------------------------------
// fp32 -> bf16 bulk convert (hs staged once; all GEMMs then take bf16 A)
// ---------------------------------------------------------------------------
__global__ void conv_f32_bf16(const float* __restrict__ in, bf16* __restrict__ out) {
    const long long N = (long long)4096 * 4096;
    long long i = ((long long)blockIdx.x * 256 + threadIdx.x) * 8;
    const long long stride = (long long)gridDim.x * 256 * 8;
    for (; i < N; i += stride) {
        float4 a = *(const float4*)(in + i);
        float4 b = *(const float4*)(in + i + 4);
        bf16x8 h;
        h[0] = (bf16)a.x; h[1] = (bf16)a.y; h[2] = (bf16)a.z; h[3] = (bf16)a.w;
        h[4] = (bf16)b.x; h[5] = (bf16)b.y; h[6] = (bf16)b.z; h[7] = (bf16)b.w;
        *(bf16x8*)(out + i) = h;
    }
}

// ---------------------------------------------------------------------------
// m97-structure GEMM: C[M=4096][col0..col0+N) = A[4096][K=4096] * Bt^T.
// 128x128 tile, BK=64, global_load_lds x16, runtime-grid XCD swizzle.
// ---------------------------------------------------------------------------
template <typename TC>
__global__ __launch_bounds__(256) void gemm_bt(const bf16* __restrict__ A,
                                               const bf16* __restrict__ Bt,
                                               TC* __restrict__ C,
                                               int lda, int ldC, int col0) {
    __shared__ __align__(16) bf16 As[128][64];
    __shared__ __align__(16) bf16 Bs[128][64];

    const int tid  = threadIdx.x;
    const int w    = tid >> 6;
    const int lane = tid & 63;
    const int quad = lane >> 4;
    const int l16  = lane & 15;
    const int wr   = (w >> 1) * 64;
    const int wc   = (w & 1) * 64;

    // XCD-aware bijective swizzle (requires nwg % 8 == 0; all launches comply)
    const u32 nbx  = gridDim.x;
    const u32 flat = blockIdx.y * nbx + blockIdx.x;
    const u32 cpx  = (nbx * gridDim.y) >> 3;
    const u32 swz  = (flat & 7) * cpx + (flat >> 3);
    const int m0   = (int)(swz / nbx) * 128;
    const int n0   = (int)(swz % nbx) * 128;

    floatx4 acc[4][4];
#pragma unroll
    for (int i = 0; i < 4; i++)
#pragma unroll
        for (int j = 0; j < 4; j++) acc[i][j] = fzero4();

    bf16* AsF = &As[0][0];
    bf16* BsF = &Bs[0][0];

    for (int k0 = 0; k0 < 4096; k0 += 64) {
        __syncthreads();
#pragma unroll
        for (int i = 0; i < 4; i++) {
            int g   = i * 256 + tid;
            int row = g >> 3;
            int col = (g & 7) << 3;
            gload16(A  + (size_t)(m0 + row) * lda  + k0 + col, AsF + (size_t)g * 8);
            gload16(Bt + (size_t)(n0 + row) * 4096 + k0 + col, BsF + (size_t)g * 8);
        }
        __syncthreads();
#pragma unroll
        for (int ks = 0; ks < 64; ks += 32) {
            bf16x8 af[4], bfg[4];
#pragma unroll
            for (int i = 0; i < 4; i++)
                af[i] = *(const bf16x8*)&As[wr + i * 16 + l16][ks + quad * 8];
#pragma unroll
            for (int j = 0; j < 4; j++)
                bfg[j] = *(const bf16x8*)&Bs[wc + j * 16 + l16][ks + quad * 8];
#pragma unroll
            for (int i = 0; i < 4; i++)
#pragma unroll
                for (int j = 0; j < 4; j++)
                    acc[i][j] = __builtin_amdgcn_mfma_f32_16x16x32_bf16(
                        af[i], bfg[j], acc[i][j], 0, 0, 0);
        }
    }

#pragma unroll
    for (int i = 0; i < 4; i++) {
#pragma unroll
        for (int r = 0; r < 4; r++) {
            int row = m0 + wr + i * 16 + quad * 4 + r;
#pragma unroll
            for (int j = 0; j < 4; j++) {
                int col = col0 + n0 + wc + j * 16 + l16;
                C[(size_t)row * ldC + col] = (TC)acc[i][j][r];
            }
        }
    }
}

// ---------------------------------------------------------------------------
// Batched strided transpose + dtype convert: out[z][c][r] = in_base(z)[r][c].
// ---------------------------------------------------------------------------
template <typename TI, typename TO>
__global__ void transpose_b(const TI* __restrict__ in, TO* __restrict__ out,
                            long long irs, long long ors,
                            int zdiv, long long zs1, long long zs2,
                            long long ozs) {
    __shared__ TI t[32][33];
    const int z = blockIdx.z;
    const TI* ip = in + (long long)(z / zdiv) * zs1 + (long long)(z % zdiv) * zs2;
    TO* op = out + (long long)z * ozs;
    const int r0 = blockIdx.y * 32, c0 = blockIdx.x * 32;
    const int tx = threadIdx.x, ty = threadIdx.y;   // block (32,8)
#pragma unroll
    for (int i = 0; i < 4; i++)
        t[ty + i * 8][tx] = ip[(long long)(r0 + ty + i * 8) * irs + c0 + tx];
    __syncthreads();
#pragma unroll
    for (int i = 0; i < 4; i++)
        op[(long long)(c0 + ty + i * 8) * ors + r0 + tx] = (TO)t[tx][ty + i * 8];
}

// ---------------------------------------------------------------------------
// RoPE on q (cols 0..4095 of fused qkv) in place, with 1/sqrt(HD) folded in.
// ---------------------------------------------------------------------------
__global__ void rope_q(bf16* __restrict__ q, const float* __restrict__ cosb,
                       const float* __restrict__ sinb) {
    const float QSC = 0.08838834764831845f;   // 1/sqrt(128), folded into Q
    size_t idx = (size_t)blockIdx.x * 256 + threadIdx.x; // B*S*NH*64
    int dp = idx & 63;
    size_t t = idx >> 6;
    int h = (int)(t % NH_);
    size_t bs = t / NH_;                 // b*S + s
    size_t base = bs * QLD + (size_t)h * HD_;
    float x1 = (float)q[base + dp];
    float x2 = (float)q[base + dp + 64];
    float c1 = cosb[bs * HD_ + dp];
    float s1 = sinb[bs * HD_ + dp];
    float c2 = cosb[bs * HD_ + dp + 64];
    float s2 = sinb[bs * HD_ + dp + 64];
    q[base + dp]      = (bf16)((x1 * c1 - x2 * s1) * QSC);
    q[base + dp + 64] = (bf16)((x2 * c2 + x1 * s2) * QSC);
}

// ---------------------------------------------------------------------------
// RoPE + repack K:  qkv cols [4096,5120)  ->  kout [b][kv][s][d]   (bf16)
// ---------------------------------------------------------------------------
__global__ void repack_k_rope(const bf16* __restrict__ qkv, bf16* __restrict__ kout,
                              const float* __restrict__ cosb,
                              const float* __restrict__ sinb) {
    size_t idx = (size_t)blockIdx.x * 256 + threadIdx.x; // B*S*NKV*64
    int dp = idx & 63;
    size_t t = idx >> 6;
    int kv = (int)(t % NKV_);
    size_t bs = t / NKV_;                // b*S + s
    int b = (int)(bs / S_);
    int s = (int)(bs % S_);
    size_t ibase = bs * QLD + (size_t)(NH_ * HD_) + (size_t)kv * HD_;
    float x1 = (float)qkv[ibase + dp];
    float x2 = (float)qkv[ibase + dp + 64];
    float c1 = cosb[bs * HD_ + dp];
    float s1 = sinb[bs * HD_ + dp];
    float c2 = cosb[bs * HD_ + dp + 64];
    float s2 = sinb[bs * HD_ + dp + 64];
    size_t obase = (((size_t)b * NKV_ + kv) * S_ + s) * HD_;
    kout[obase + dp]      = (bf16)(x1 * c1 - x2 * s1);
    kout[obase + dp + 64] = (bf16)(x2 * c2 + x1 * s2);
}

// ---------------------------------------------------------------------------
// Causal flash attention v3.
//  - Pairing: block bx does qb=bx (pass0) and qb=15-bx (pass1) => 34 tile-
//    iters per block, 512 blocks = exactly 2 blocks/CU, zero tail.
//    In-place safe: pass0 writes rows qb<8 only; pass1 reads rows qb>=8 only.
//  - Double-buffered K/V via global_load_lds; stage(j+1) issued BEFORE
//    compute(j); ONE __syncthreads per iter (late vmcnt drain) -> latency hid.
//  - VALU diet: scale pre-folded into Q (rope_q); causal mask only on the
//    <=1 tile/wave intersecting the diagonal; defer-max (T13, THR=8) skips
//    O-rescale when the running max doesn't grow.
// ---------------------------------------------------------------------------
__global__ __launch_bounds__(256) void flash_fwd(const bf16* __restrict__ Q,
                                                 const bf16* __restrict__ Kp,
                                                 const bf16* __restrict__ Vt,
                                                 bf16* __restrict__ O) {
    __shared__ __align__(16) bf16 smem[32768];   // 64 KiB: 2 x (Ks 8K + Vs 8K els)

    const int bh = blockIdx.y;
    const int b = bh >> 5, h = bh & 31, kv = h >> 2;   // NH=32, NH/NKV=4
    const int tid = threadIdx.x, w = tid >> 6, lane = tid & 63;
    const int l32 = lane & 31, hlf = lane >> 5;

    const bf16* Kb = Kp + (size_t)(b * NKV_ + kv) * S_ * HD_;
    const bf16* Vb = Vt + (size_t)(b * NKV_ + kv) * (size_t)HD_ * S_;
    const bf16* Qbase = Q + (size_t)b * S_ * QLD + (size_t)h * HD_;
    bf16* Obase = O + (size_t)b * S_ * QLD + (size_t)h * HD_;

    auto stage = [&](int kbase, bf16* KsB, bf16* VsB) {
#pragma unroll
        for (int i = 0; i < 4; i++) {
            int G = i * 256 + tid;
            int r = G >> 4, gp = G & 15;
            int gl = gp ^ (r & 15);
            gload16(Kb + (size_t)(kbase + r) * HD_ + gl * 8, KsB + (size_t)G * 8);
        }
#pragma unroll
        for (int i = 0; i < 4; i++) {
            int G = i * 256 + tid;
            int R = G >> 4, gp = G & 15;
            int g16 = gp ^ (R & 15);
            int d = R * 2 + (g16 >> 3);
            int kg = g16 & 7;
            gload16(Vb + (size_t)d * S_ + kbase + kg * 8, VsB + (size_t)G * 8);
        }
    };

    for (int pass = 0; pass < 2; ++pass) {
        const int qb = pass ? (15 - (int)blockIdx.x) : (int)blockIdx.x;
        const int q0 = qb * 128;
        const int wqmin = q0 + w * 32;
        const int wqmax = wqmin + 31;
        const int qrow = wqmin + l32;

        // Q fragments (B-operand: lane = q-col l32, k-slice hlf*8)
        const bf16* Qr = Qbase + (size_t)qrow * QLD;
        bf16x8 qf[8];
#pragma unroll
        for (int ks = 0; ks < 8; ks++)
            qf[ks] = *(const bf16x8*)(Qr + ks * 16 + hlf * 8);

        floatx16 ot[4];
#pragma unroll
        for (int dt = 0; dt < 4; dt++)
#pragma unroll
            for (int r = 0; r < 16; r++) ot[dt][r] = 0.f;
        float mi = -1e30f, li = 0.f;

        if (pass) __syncthreads();     // previous epilogue's LDS readers done
        stage(0, smem, smem + 8192);
        __syncthreads();               // tile 0 visible

        auto compute = [&](int kbase, const bf16* KsB, const bf16* VsB) {
            if (kbase > wqmax) return;             // wave-uniform skip
            floatx16 st[2];
#pragma unroll
            for (int n = 0; n < 2; n++)
#pragma unroll
                for (int r = 0; r < 16; r++) st[n][r] = 0.f;
#pragma unroll
            for (int ks = 0; ks < 8; ks++) {
                int phys = (ks * 2 + hlf) ^ (l32 & 15);
#pragma unroll
                for (int n = 0; n < 2; n++) {
                    bf16x8 kf = *(const bf16x8*)(KsB + (size_t)(n * 32 + l32) * 128 + phys * 8);
                    st[n] = __builtin_amdgcn_mfma_f32_32x32x16_bf16(
                        kf, qf[ks], st[n], 0, 0, 0);
                }
            }
            if (kbase + 63 > wqmin) {   // only the diagonal-intersecting tile
#pragma unroll
                for (int n = 0; n < 2; n++)
#pragma unroll
                    for (int r = 0; r < 16; r++) {
                        int key = kbase + n * 32 + (r & 3) + 8 * (r >> 2) + 4 * hlf;
                        if (key > qrow) st[n][r] = -1e30f;
                    }
            }
            // tile max (lane-local + pair combine)
            float m = st[0][0];
#pragma unroll
            for (int r = 1; r < 16; r++) m = fmaxf(m, st[0][r]);
#pragma unroll
            for (int r = 0; r < 16; r++) m = fmaxf(m, st[1][r]);
            m = fmaxf(m, __shfl_xor(m, 32));
            // defer-max: rescale only when the max actually grows (THR=8)
            if (!__all(m <= mi + 8.f)) {
                float mn = fmaxf(mi, m);
                float al = __expf(mi - mn);
                mi = mn;
                li *= al;
#pragma unroll
                for (int dt = 0; dt < 4; dt++)
#pragma unroll
                    for (int r = 0; r < 16; r++) ot[dt][r] *= al;
            }
            float ls = 0.f;
#pragma unroll
            for (int n = 0; n < 2; n++)
#pragma unroll
                for (int r = 0; r < 16; r++) {
                    float p = __expf(st[n][r] - mi);
                    st[n][r] = p;
                    ls += p;
                }
            ls += __shfl_xor(ls, 32);
            li += ls;

            // repack P -> PV B-frags (8 consecutive keys/lane via lane^32 swap)
            bf16x8 pb[4];
#pragma unroll
            for (int ks2 = 0; ks2 < 4; ks2++) {
                const int n = ks2 >> 1;
                const int rb = (ks2 & 1) * 8;
                float s0 = hlf ? st[n][rb + 0] : st[n][rb + 4];
                float s1 = hlf ? st[n][rb + 1] : st[n][rb + 5];
                float s2 = hlf ? st[n][rb + 2] : st[n][rb + 6];
                float s3 = hlf ? st[n][rb + 3] : st[n][rb + 7];
                float r0 = __shfl_xor(s0, 32);
                float r1 = __shfl_xor(s1, 32);
                float r2 = __shfl_xor(s2, 32);
                float r3 = __shfl_xor(s3, 32);
                float e0, e1, e2, e3, e4, e5, e6, e7;
                if (hlf == 0) {
                    e0 = st[n][rb + 0]; e1 = st[n][rb + 1];
                    e2 = st[n][rb + 2]; e3 = st[n][rb + 3];
                    e4 = r0; e5 = r1; e6 = r2; e7 = r3;
                } else {
                    e0 = r0; e1 = r1; e2 = r2; e3 = r3;
                    e4 = st[n][rb + 4]; e5 = st[n][rb + 5];
                    e6 = st[n][rb + 6]; e7 = st[n][rb + 7];
                }
                bf16x8 t;
                t[0] = (bf16)e0; t[1] = (bf16)e1; t[2] = (bf16)e2; t[3] = (bf16)e3;
                t[4] = (bf16)e4; t[5] = (bf16)e5; t[6] = (bf16)e6; t[7] = (bf16)e7;
                pb[ks2] = t;
            }

            // PV: O^T[d][q] += V^T[d][k] * P^T[k][q]
#pragma unroll
            for (int ks2 = 0; ks2 < 4; ks2++) {
#pragma unroll
                for (int dt = 0; dt < 4; dt++) {
                    int d = dt * 32 + l32;
                    int g16 = ((d & 1) * 8 + ks2 * 2 + hlf) ^ ((d >> 1) & 15);
                    bf16x8 vf = *(const bf16x8*)(VsB + (size_t)(d >> 1) * 128 + g16 * 8);
                    ot[dt] = __builtin_amdgcn_mfma_f32_32x32x16_bf16(
                        vf, pb[ks2], ot[dt], 0, 0, 0);
                }
            }
        };

        const int nT = 2 * qb + 2;     // always even
        for (int j = 0; j < nT; j += 2) {
            stage((j + 1) * 64, smem + 16384, smem + 24576);  // -> buf1
            compute(j * 64, smem, smem + 8192);               // from buf0
            __syncthreads();                                  // drain + barrier
            if (j + 2 < nT) stage((j + 2) * 64, smem, smem + 8192);  // -> buf0
            compute((j + 1) * 64, smem + 16384, smem + 24576);       // from buf1
            __syncthreads();
        }

        // epilogue: O^T regs -> LDS (row-major per q) -> coalesced global store
        {
            const float inv = 1.f / li;
            bf16* Os = smem + (size_t)w * 32 * 136;   // stride 136 els = 272 B
#pragma unroll
            for (int dt = 0; dt < 4; dt++)
#pragma unroll
                for (int r = 0; r < 16; r++) {
                    int d = dt * 32 + (r & 3) + 8 * (r >> 2) + 4 * hlf;
                    Os[l32 * 136 + d] = (bf16)(ot[dt][r] * inv);
                }
        }
        __syncthreads();
        {
#pragma unroll
            for (int i = 0; i < 8; i++) {
                int u = i * 256 + tid;
                int qa = u >> 4, gr = u & 15;
                bf16x8 v = *(const bf16x8*)(smem + (size_t)qa * 136 + gr * 8);
                *(bf16x8*)(Obase + (size_t)(q0 + qa) * QLD + gr * 8) = v;
            }
        }
    }
}

// ---------------------------------------------------------------------------
extern "C" void kernel_launch(void* const* d_in, const int* in_sizes, int n_in,
                              void* d_out, int out_size, void* d_ws, size_t ws_size,
                              hipStream_t stream) {
    const float* hs   = (const float*)d_in[0];
    const float* cosb = (const float*)d_in[1];
    const float* sinb = (const float*)d_in[2];
    const float* wq   = (const float*)d_in[3];
    const float* wk   = (const float*)d_in[4];
    const float* wv   = (const float*)d_in[5];
    const float* wo   = (const float*)d_in[6];
    float* out = (float*)d_out;
    (void)in_sizes; (void)n_in; (void)out_size;

    // 72 MiB workspace (proven available in earlier sessions)
    const size_t NEED = (size_t)72 * 1024 * 1024;
    if (ws_size < NEED) return;

    char* ws = (char*)d_ws;
    bf16* qkv = (bf16*)ws;                                   // 48 MiB: [4096][6144]
    bf16* R1  = (bf16*)(ws + (size_t)48 * 1024 * 1024);      // 24 MiB shared region

    bf16* hsb = (bf16*)d_out;                                // 32 of 64 MiB

    dim3 tb(32, 8, 1);

    conv_f32_bf16<<<2048, 256, 0, stream>>>(hs, hsb);

    // QKV projection: 2 strips of 3072 cols (768-block GEMMs)
    // strip0: wq cols [0,3072)
    transpose_b<float, bf16><<<dim3(96, 128, 1), tb, 0, stream>>>(
        wq, R1, 4096, 4096, 1, 0, 0, 0);
    gemm_bt<bf16><<<dim3(24, 32), 256, 0, stream>>>(
        hsb, R1, qkv, 4096, QLD, 0);
    // strip1: wq cols [3072,4096) ++ wk ++ wv
    transpose_b<float, bf16><<<dim3(32, 128, 1), tb, 0, stream>>>(
        wq + 3072, R1, 4096, 4096, 1, 0, 0, 0);
    transpose_b<float, bf16><<<dim3(32, 128, 1), tb, 0, stream>>>(
        wk, R1 + (size_t)1024 * 4096, 1024, 4096, 1, 0, 0, 0);
    transpose_b<float, bf16><<<dim3(32, 128, 1), tb, 0, stream>>>(
        wv, R1 + (size_t)2048 * 4096, 1024, 4096, 1, 0, 0, 0);
    gemm_bt<bf16><<<dim3(24, 32), 256, 0, stream>>>(
        hsb, R1, qkv, 4096, QLD, 3072);

    // rope q in place (scale folded); repack K (rope) and transpose V
    rope_q<<<(B_ * S_ * NH_ * 64) / 256, 256, 0, stream>>>(qkv, cosb, sinb);
    bf16* Kpk = R1;                                          // 8 MiB
    bf16* Vtv = R1 + (size_t)B_ * NKV_ * S_ * HD_;           // 8 MiB
    repack_k_rope<<<(B_ * S_ * NKV_ * 64) / 256, 256, 0, stream>>>(
        qkv, Kpk, cosb, sinb);
    // V: qkv cols [5120,6144) [b][s][kv][d] -> [b*kv][d][s]
    transpose_b<bf16, bf16><<<dim3(HD_ / 32, S_ / 32, B_ * NKV_), tb, 0, stream>>>(
        qkv + NH_ * HD_ + NKV_ * HD_, Vtv, QLD, S_,
        NKV_, (long long)S_ * QLD, HD_, (long long)HD_ * S_);

    // attention v3: paired blocks, grid (8, 64)
    flash_fwd<<<dim3(8, B_ * NH_), 256, 0, stream>>>(qkv, Kpk, Vtv, qkv);

    // output projection: 2 strips of 2048 cols, fp32 out (overwrites hsb)
    for (int s = 0; s < 2; s++) {
        transpose_b<float, bf16><<<dim3(64, 128, 1), tb, 0, stream>>>(
            wo + 2048 * s, R1, 4096, 4096, 1, 0, 0, 0);
        gemm_bt<float><<<dim3(16, 32), 256, 0, stream>>>(
            qkv, R1, out, QLD, 4096, 2048 * s);
    }
}

// Round 4
// 975.207 us; speedup vs baseline: 1.6032x; 1.0307x over previous
//
#include <hip/hip_runtime.h>

#define B_ 2
#define S_ 2048
#define H_ 4096
#define NH_ 32
#define NKV_ 8
#define HD_ 128
#define QLD 6144   // fused qkv row stride = NH*HD + 2*NKV*HD

typedef __bf16 bf16;
typedef __bf16 bf16x8 __attribute__((ext_vector_type(8)));
typedef float floatx4 __attribute__((ext_vector_type(4)));
typedef float floatx16 __attribute__((ext_vector_type(16)));
typedef unsigned int u32;

static __device__ __forceinline__ floatx4 fzero4() {
    floatx4 v; v[0] = 0.f; v[1] = 0.f; v[2] = 0.f; v[3] = 0.f; return v;
}

// async global -> LDS, 16 bytes per lane (dest linear in lane; src per-lane)
static __device__ __forceinline__ void gload16(const bf16* g, bf16* l) {
    __builtin_amdgcn_global_load_lds((const __attribute__((address_space(1))) u32*)g,
                                     (__attribute__((address_space(3))) u32*)l,
                                     16, 0, 0);
}

// ---------------------------------------------------------------------------
// fp32 -> bf16 bulk convert (hs staged once; all GEMMs then take bf16 A)
// ---------------------------------------------------------------------------
__global__ void conv_f32_bf16(const float* __restrict__ in, bf16* __restrict__ out) {
    const long long N = (long long)4096 * 4096;
    long long i = ((long long)blockIdx.x * 256 + threadIdx.x) * 8;
    const long long stride = (long long)gridDim.x * 256 * 8;
    for (; i < N; i += stride) {
        float4 a = *(const float4*)(in + i);
        float4 b = *(const float4*)(in + i + 4);
        bf16x8 h;
        h[0] = (bf16)a.x; h[1] = (bf16)a.y; h[2] = (bf16)a.z; h[3] = (bf16)a.w;
        h[4] = (bf16)b.x; h[5] = (bf16)b.y; h[6] = (bf16)b.z; h[7] = (bf16)b.w;
        *(bf16x8*)(out + i) = h;
    }
}

// ---------------------------------------------------------------------------
// 256x256-tile counted-vmcnt GEMM (m201-style schedule, tile-granular safe
// rotation).  512 threads = 8 waves (2M x 4N), per-wave 128x64 output,
// BK=64, K=4096.  LDS 128 KiB = 2 slots x (A 256x64 + B 256x64) bf16,
// T2 XOR-swizzled (granule ^= row&7).  vmcnt never drains to 0 in-loop.
// B^T may be split across two regions at row nsplit (256-aligned).
// ---------------------------------------------------------------------------
template <typename TC>
__global__ __launch_bounds__(512) void gemm256(const bf16* __restrict__ A,
                                               const bf16* __restrict__ Bt0,
                                               const bf16* __restrict__ Bt1,
                                               int nsplit,
                                               TC* __restrict__ C,
                                               int lda, int ldC, int col0) {
    __shared__ __align__(16) bf16 lds[2][2][2][8192]; // [slot][op A/B][half][128*64]

    const int tid  = threadIdx.x;
    const int wid  = tid >> 6;
    const int lane = tid & 63;
    const int quad = lane >> 4;
    const int l16  = lane & 15;
    const int wr   = wid >> 2;       // 0..1  (M)
    const int wc   = wid & 3;        // 0..3  (N)

    // XCD-aware bijective swizzle (nwg % 8 == 0 for all launches)
    const u32 nbx  = gridDim.x;
    const u32 flat = blockIdx.y * nbx + blockIdx.x;
    const u32 cpx  = (nbx * gridDim.y) >> 3;
    const u32 swz  = (flat & 7) * cpx + (flat >> 3);
    const int m0   = (int)(swz / nbx) * 256;
    const int n0t  = (int)(swz % nbx) * 256;

    const bf16* Bt = (n0t < nsplit) ? Bt0 + (size_t)n0t * 4096
                                    : Bt1 + (size_t)(n0t - nsplit) * 4096;

    floatx4 acc[8][4];
#pragma unroll
    for (int i = 0; i < 8; i++)
#pragma unroll
        for (int j = 0; j < 4; j++) acc[i][j] = fzero4();

    // stage chunk c (0..7) of the K-tile at k0 into slot s.
    // c: 0-1 = A half0, 2-3 = A half1, 4-5 = B half0, 6-7 = B half1.
    // Each chunk = 512 granules of 16 B; LDS dest linear, global src
    // pre-swizzled (granule ^= row&7) so swizzled reads see logical data.
    auto stageChunk = [&](int s, int k0, int c) {
        const int op   = c >> 2;
        const int half = (c >> 1) & 1;
        const int r    = (c & 1) * 64 + (tid >> 3);
        const int gs   = tid & 7;
        const int glog = gs ^ (r & 7);
        const int G    = (c & 1) * 512 + tid;
        const bf16* src = op
            ? Bt + (size_t)(half * 128 + r) * 4096 + k0 + glog * 8
            : A + (size_t)(m0 + half * 128 + r) * lda + k0 + glog * 8;
        gload16(src, &lds[s][op][half][(size_t)G * 8]);
    };

    const int NT = 4096 / 64;   // 64 K-tiles
    // prologue: tiles 0 and 1
#pragma unroll
    for (int c = 0; c < 8; c++) stageChunk(0, 0, c);
#pragma unroll
    for (int c = 0; c < 8; c++) stageChunk(1, 64, c);

    for (int g = 0; g < NT; ++g) {
        const int s = g & 1;
        // stage tile g+1 into slot (g+1)&1 (freed by tile g-1 at the end of
        // group g-1; issue is after that barrier in program order)
        if (g >= 1 && g + 1 < NT) {
            const int kn = (g + 1) * 64;
#pragma unroll
            for (int c = 0; c < 8; c++) stageChunk((g + 1) & 1, kn, c);
        }
        // tile g arrived when <=8 newer loads (tile g+1) remain outstanding
        if (g + 1 < NT) asm volatile("s_waitcnt vmcnt(8)" ::: "memory");
        else            asm volatile("s_waitcnt vmcnt(0)" ::: "memory");
        __builtin_amdgcn_sched_barrier(0);
        __builtin_amdgcn_s_barrier();

        // 4 phases; phase p computes quadrant (qm = p>>1, qn = p&1)
#pragma unroll
        for (int p = 0; p < 4; p++) {
            const int qm = p >> 1, qn = p & 1;
            bf16x8 af[4][2], bfr[2][2];
#pragma unroll
            for (int i = 0; i < 4; i++) {
                const int r = (qm * 4 + i) * 16 + l16;
#pragma unroll
                for (int ks = 0; ks < 2; ks++)
                    af[i][ks] = *(const bf16x8*)&lds[s][0][wr]
                        [(size_t)r * 64 + ((ks * 4 + quad) ^ (r & 7)) * 8];
            }
#pragma unroll
            for (int j = 0; j < 2; j++) {
                const int rb = (wc & 1) * 64 + (qn * 2 + j) * 16 + l16;
#pragma unroll
                for (int ks = 0; ks < 2; ks++)
                    bfr[j][ks] = *(const bf16x8*)&lds[s][1][wc >> 1]
                        [(size_t)rb * 64 + ((ks * 4 + quad) ^ (rb & 7)) * 8];
            }
            __builtin_amdgcn_s_barrier();
            __builtin_amdgcn_s_setprio(1);
#pragma unroll
            for (int i = 0; i < 4; i++)
#pragma unroll
                for (int j = 0; j < 2; j++)
#pragma unroll
                    for (int ks = 0; ks < 2; ks++)
                        acc[qm * 4 + i][qn * 2 + j] =
                            __builtin_amdgcn_mfma_f32_16x16x32_bf16(
                                af[i][ks], bfr[j][ks],
                                acc[qm * 4 + i][qn * 2 + j], 0, 0, 0);
            __builtin_amdgcn_s_setprio(0);
            __builtin_amdgcn_s_barrier();
        }
    }

    // epilogue: D layout row = quad*4 + rr, col = l16 (m89-verified)
#pragma unroll
    for (int fa = 0; fa < 8; fa++) {
#pragma unroll
        for (int rr = 0; rr < 4; rr++) {
            const int row = m0 + wr * 128 + fa * 16 + quad * 4 + rr;
#pragma unroll
            for (int fb = 0; fb < 4; fb++) {
                const int col = col0 + n0t + wc * 64 + fb * 16 + l16;
                C[(size_t)row * ldC + col] = (TC)acc[fa][fb][rr];
            }
        }
    }
}

// ---------------------------------------------------------------------------
// Batched strided transpose + dtype convert: out[z][c][r] = in_base(z)[r][c].
// ---------------------------------------------------------------------------
template <typename TI, typename TO>
__global__ void transpose_b(const TI* __restrict__ in, TO* __restrict__ out,
                            long long irs, long long ors,
                            int zdiv, long long zs1, long long zs2,
                            long long ozs) {
    __shared__ TI t[32][33];
    const int z = blockIdx.z;
    const TI* ip = in + (long long)(z / zdiv) * zs1 + (long long)(z % zdiv) * zs2;
    TO* op = out + (long long)z * ozs;
    const int r0 = blockIdx.y * 32, c0 = blockIdx.x * 32;
    const int tx = threadIdx.x, ty = threadIdx.y;   // block (32,8)
#pragma unroll
    for (int i = 0; i < 4; i++)
        t[ty + i * 8][tx] = ip[(long long)(r0 + ty + i * 8) * irs + c0 + tx];
    __syncthreads();
#pragma unroll
    for (int i = 0; i < 4; i++)
        op[(long long)(c0 + ty + i * 8) * ors + r0 + tx] = (TO)t[tx][ty + i * 8];
}

// ---------------------------------------------------------------------------
// RoPE on q (cols 0..4095 of fused qkv) in place, with 1/sqrt(HD) folded in.
// ---------------------------------------------------------------------------
__global__ void rope_q(bf16* __restrict__ q, const float* __restrict__ cosb,
                       const float* __restrict__ sinb) {
    const float QSC = 0.08838834764831845f;   // 1/sqrt(128), folded into Q
    size_t idx = (size_t)blockIdx.x * 256 + threadIdx.x; // B*S*NH*64
    int dp = idx & 63;
    size_t t = idx >> 6;
    int h = (int)(t % NH_);
    size_t bs = t / NH_;                 // b*S + s
    size_t base = bs * QLD + (size_t)h * HD_;
    float x1 = (float)q[base + dp];
    float x2 = (float)q[base + dp + 64];
    float c1 = cosb[bs * HD_ + dp];
    float s1 = sinb[bs * HD_ + dp];
    float c2 = cosb[bs * HD_ + dp + 64];
    float s2 = sinb[bs * HD_ + dp + 64];
    q[base + dp]      = (bf16)((x1 * c1 - x2 * s1) * QSC);
    q[base + dp + 64] = (bf16)((x2 * c2 + x1 * s2) * QSC);
}

// ---------------------------------------------------------------------------
// RoPE + repack K:  qkv cols [4096,5120)  ->  kout [b][kv][s][d]   (bf16)
// ---------------------------------------------------------------------------
__global__ void repack_k_rope(const bf16* __restrict__ qkv, bf16* __restrict__ kout,
                              const float* __restrict__ cosb,
                              const float* __restrict__ sinb) {
    size_t idx = (size_t)blockIdx.x * 256 + threadIdx.x; // B*S*NKV*64
    int dp = idx & 63;
    size_t t = idx >> 6;
    int kv = (int)(t % NKV_);
    size_t bs = t / NKV_;                // b*S + s
    int b = (int)(bs / S_);
    int s = (int)(bs % S_);
    size_t ibase = bs * QLD + (size_t)(NH_ * HD_) + (size_t)kv * HD_;
    float x1 = (float)qkv[ibase + dp];
    float x2 = (float)qkv[ibase + dp + 64];
    float c1 = cosb[bs * HD_ + dp];
    float s1 = sinb[bs * HD_ + dp];
    float c2 = cosb[bs * HD_ + dp + 64];
    float s2 = sinb[bs * HD_ + dp + 64];
    size_t obase = (((size_t)b * NKV_ + kv) * S_ + s) * HD_;
    kout[obase + dp]      = (bf16)(x1 * c1 - x2 * s1);
    kout[obase + dp + 64] = (bf16)(x2 * c2 + x1 * s2);
}

// ---------------------------------------------------------------------------
// Causal flash attention v3 (unchanged from round 3: paired blocks, double-
// buffered K/V via global_load_lds, swizzled LDS, defer-max, one barrier/iter).
// ---------------------------------------------------------------------------
__global__ __launch_bounds__(256) void flash_fwd(const bf16* __restrict__ Q,
                                                 const bf16* __restrict__ Kp,
                                                 const bf16* __restrict__ Vt,
                                                 bf16* __restrict__ O) {
    __shared__ __align__(16) bf16 smem[32768];   // 64 KiB: 2 x (Ks 8K + Vs 8K els)

    const int bh = blockIdx.y;
    const int b = bh >> 5, h = bh & 31, kv = h >> 2;   // NH=32, NH/NKV=4
    const int tid = threadIdx.x, w = tid >> 6, lane = tid & 63;
    const int l32 = lane & 31, hlf = lane >> 5;

    const bf16* Kb = Kp + (size_t)(b * NKV_ + kv) * S_ * HD_;
    const bf16* Vb = Vt + (size_t)(b * NKV_ + kv) * (size_t)HD_ * S_;
    const bf16* Qbase = Q + (size_t)b * S_ * QLD + (size_t)h * HD_;
    bf16* Obase = O + (size_t)b * S_ * QLD + (size_t)h * HD_;

    auto stage = [&](int kbase, bf16* KsB, bf16* VsB) {
#pragma unroll
        for (int i = 0; i < 4; i++) {
            int G = i * 256 + tid;
            int r = G >> 4, gp = G & 15;
            int gl = gp ^ (r & 15);
            gload16(Kb + (size_t)(kbase + r) * HD_ + gl * 8, KsB + (size_t)G * 8);
        }
#pragma unroll
        for (int i = 0; i < 4; i++) {
            int G = i * 256 + tid;
            int R = G >> 4, gp = G & 15;
            int g16 = gp ^ (R & 15);
            int d = R * 2 + (g16 >> 3);
            int kg = g16 & 7;
            gload16(Vb + (size_t)d * S_ + kbase + kg * 8, VsB + (size_t)G * 8);
        }
    };

    for (int pass = 0; pass < 2; ++pass) {
        const int qb = pass ? (15 - (int)blockIdx.x) : (int)blockIdx.x;
        const int q0 = qb * 128;
        const int wqmin = q0 + w * 32;
        const int wqmax = wqmin + 31;
        const int qrow = wqmin + l32;

        const bf16* Qr = Qbase + (size_t)qrow * QLD;
        bf16x8 qf[8];
#pragma unroll
        for (int ks = 0; ks < 8; ks++)
            qf[ks] = *(const bf16x8*)(Qr + ks * 16 + hlf * 8);

        floatx16 ot[4];
#pragma unroll
        for (int dt = 0; dt < 4; dt++)
#pragma unroll
            for (int r = 0; r < 16; r++) ot[dt][r] = 0.f;
        float mi = -1e30f, li = 0.f;

        if (pass) __syncthreads();     // previous epilogue's LDS readers done
        stage(0, smem, smem + 8192);
        __syncthreads();               // tile 0 visible

        auto compute = [&](int kbase, const bf16* KsB, const bf16* VsB) {
            if (kbase > wqmax) return;             // wave-uniform skip
            floatx16 st[2];
#pragma unroll
            for (int n = 0; n < 2; n++)
#pragma unroll
                for (int r = 0; r < 16; r++) st[n][r] = 0.f;
#pragma unroll
            for (int ks = 0; ks < 8; ks++) {
                int phys = (ks * 2 + hlf) ^ (l32 & 15);
#pragma unroll
                for (int n = 0; n < 2; n++) {
                    bf16x8 kf = *(const bf16x8*)(KsB + (size_t)(n * 32 + l32) * 128 + phys * 8);
                    st[n] = __builtin_amdgcn_mfma_f32_32x32x16_bf16(
                        kf, qf[ks], st[n], 0, 0, 0);
                }
            }
            if (kbase + 63 > wqmin) {   // only the diagonal-intersecting tile
#pragma unroll
                for (int n = 0; n < 2; n++)
#pragma unroll
                    for (int r = 0; r < 16; r++) {
                        int key = kbase + n * 32 + (r & 3) + 8 * (r >> 2) + 4 * hlf;
                        if (key > qrow) st[n][r] = -1e30f;
                    }
            }
            float m = st[0][0];
#pragma unroll
            for (int r = 1; r < 16; r++) m = fmaxf(m, st[0][r]);
#pragma unroll
            for (int r = 0; r < 16; r++) m = fmaxf(m, st[1][r]);
            m = fmaxf(m, __shfl_xor(m, 32));
            if (!__all(m <= mi + 8.f)) {
                float mn = fmaxf(mi, m);
                float al = __expf(mi - mn);
                mi = mn;
                li *= al;
#pragma unroll
                for (int dt = 0; dt < 4; dt++)
#pragma unroll
                    for (int r = 0; r < 16; r++) ot[dt][r] *= al;
            }
            float ls = 0.f;
#pragma unroll
            for (int n = 0; n < 2; n++)
#pragma unroll
                for (int r = 0; r < 16; r++) {
                    float p = __expf(st[n][r] - mi);
                    st[n][r] = p;
                    ls += p;
                }
            ls += __shfl_xor(ls, 32);
            li += ls;

            bf16x8 pb[4];
#pragma unroll
            for (int ks2 = 0; ks2 < 4; ks2++) {
                const int n = ks2 >> 1;
                const int rb = (ks2 & 1) * 8;
                float s0 = hlf ? st[n][rb + 0] : st[n][rb + 4];
                float s1 = hlf ? st[n][rb + 1] : st[n][rb + 5];
                float s2 = hlf ? st[n][rb + 2] : st[n][rb + 6];
                float s3 = hlf ? st[n][rb + 3] : st[n][rb + 7];
                float r0 = __shfl_xor(s0, 32);
                float r1 = __shfl_xor(s1, 32);
                float r2 = __shfl_xor(s2, 32);
                float r3 = __shfl_xor(s3, 32);
                float e0, e1, e2, e3, e4, e5, e6, e7;
                if (hlf == 0) {
                    e0 = st[n][rb + 0]; e1 = st[n][rb + 1];
                    e2 = st[n][rb + 2]; e3 = st[n][rb + 3];
                    e4 = r0; e5 = r1; e6 = r2; e7 = r3;
                } else {
                    e0 = r0; e1 = r1; e2 = r2; e3 = r3;
                    e4 = st[n][rb + 4]; e5 = st[n][rb + 5];
                    e6 = st[n][rb + 6]; e7 = st[n][rb + 7];
                }
                bf16x8 t;
                t[0] = (bf16)e0; t[1] = (bf16)e1; t[2] = (bf16)e2; t[3] = (bf16)e3;
                t[4] = (bf16)e4; t[5] = (bf16)e5; t[6] = (bf16)e6; t[7] = (bf16)e7;
                pb[ks2] = t;
            }

#pragma unroll
            for (int ks2 = 0; ks2 < 4; ks2++) {
#pragma unroll
                for (int dt = 0; dt < 4; dt++) {
                    int d = dt * 32 + l32;
                    int g16 = ((d & 1) * 8 + ks2 * 2 + hlf) ^ ((d >> 1) & 15);
                    bf16x8 vf = *(const bf16x8*)(VsB + (size_t)(d >> 1) * 128 + g16 * 8);
                    ot[dt] = __builtin_amdgcn_mfma_f32_32x32x16_bf16(
                        vf, pb[ks2], ot[dt], 0, 0, 0);
                }
            }
        };

        const int nT = 2 * qb + 2;     // always even
        for (int j = 0; j < nT; j += 2) {
            stage((j + 1) * 64, smem + 16384, smem + 24576);  // -> buf1
            compute(j * 64, smem, smem + 8192);               // from buf0
            __syncthreads();                                  // drain + barrier
            if (j + 2 < nT) stage((j + 2) * 64, smem, smem + 8192);  // -> buf0
            compute((j + 1) * 64, smem + 16384, smem + 24576);       // from buf1
            __syncthreads();
        }

        {
            const float inv = 1.f / li;
            bf16* Os = smem + (size_t)w * 32 * 136;   // stride 136 els = 272 B
#pragma unroll
            for (int dt = 0; dt < 4; dt++)
#pragma unroll
                for (int r = 0; r < 16; r++) {
                    int d = dt * 32 + (r & 3) + 8 * (r >> 2) + 4 * hlf;
                    Os[l32 * 136 + d] = (bf16)(ot[dt][r] * inv);
                }
        }
        __syncthreads();
        {
#pragma unroll
            for (int i = 0; i < 8; i++) {
                int u = i * 256 + tid;
                int qa = u >> 4, gr = u & 15;
                bf16x8 v = *(const bf16x8*)(smem + (size_t)qa * 136 + gr * 8);
                *(bf16x8*)(Obase + (size_t)(q0 + qa) * QLD + gr * 8) = v;
            }
        }
    }
}

// ---------------------------------------------------------------------------
extern "C" void kernel_launch(void* const* d_in, const int* in_sizes, int n_in,
                              void* d_out, int out_size, void* d_ws, size_t ws_size,
                              hipStream_t stream) {
    const float* hs   = (const float*)d_in[0];
    const float* cosb = (const float*)d_in[1];
    const float* sinb = (const float*)d_in[2];
    const float* wq   = (const float*)d_in[3];
    const float* wk   = (const float*)d_in[4];
    const float* wv   = (const float*)d_in[5];
    const float* wo   = (const float*)d_in[6];
    float* out = (float*)d_out;
    (void)in_sizes; (void)n_in; (void)out_size;

    // 72 MiB workspace (proven available in earlier sessions)
    const size_t NEED = (size_t)72 * 1024 * 1024;
    if (ws_size < NEED) return;

    char* ws = (char*)d_ws;
    bf16* qkv = (bf16*)ws;                                   // 48 MiB: [4096][6144]
    bf16* R1  = (bf16*)(ws + (size_t)48 * 1024 * 1024);      // 24 MiB shared region

    // d_out doubles as scratch until the WO GEMM finally writes it:
    bf16* hsb = (bf16*)d_out;                                // [0,32 MiB): hs in bf16
    bf16* BtHi = (bf16*)((char*)d_out + (size_t)32 * 1024 * 1024); // [32,56): B^T hi

    dim3 tb(32, 8, 1);

    conv_f32_bf16<<<2048, 256, 0, stream>>>(hs, hsb);

    // fused QKV weight^T: rows [0,3072) -> R1 (wq cols 0..3071);
    // rows [3072,6144) -> BtHi (wq cols 3072..4095 ++ wk ++ wv)
    transpose_b<float, bf16><<<dim3(96, 128, 1), tb, 0, stream>>>(
        wq, R1, 4096, 4096, 1, 0, 0, 0);
    transpose_b<float, bf16><<<dim3(32, 128, 1), tb, 0, stream>>>(
        wq + 3072, BtHi, 4096, 4096, 1, 0, 0, 0);
    transpose_b<float, bf16><<<dim3(32, 128, 1), tb, 0, stream>>>(
        wk, BtHi + (size_t)1024 * 4096, 1024, 4096, 1, 0, 0, 0);
    transpose_b<float, bf16><<<dim3(32, 128, 1), tb, 0, stream>>>(
        wv, BtHi + (size_t)2048 * 4096, 1024, 4096, 1, 0, 0, 0);

    // QKV projection: ONE 384-block launch, N = 6144
    gemm256<bf16><<<dim3(24, 16), 512, 0, stream>>>(
        hsb, R1, BtHi, 3072, qkv, 4096, QLD, 0);

    // rope q in place (scale folded); repack K (rope) and transpose V
    rope_q<<<(B_ * S_ * NH_ * 64) / 256, 256, 0, stream>>>(qkv, cosb, sinb);
    bf16* Kpk = R1;                                          // 8 MiB
    bf16* Vtv = R1 + (size_t)B_ * NKV_ * S_ * HD_;           // 8 MiB
    repack_k_rope<<<(B_ * S_ * NKV_ * 64) / 256, 256, 0, stream>>>(
        qkv, Kpk, cosb, sinb);
    // V: qkv cols [5120,6144) [b][s][kv][d] -> [b*kv][d][s]
    transpose_b<bf16, bf16><<<dim3(HD_ / 32, S_ / 32, B_ * NKV_), tb, 0, stream>>>(
        qkv + NH_ * HD_ + NKV_ * HD_, Vtv, QLD, S_,
        NKV_, (long long)S_ * QLD, HD_, (long long)HD_ * S_);

    // attention v3: paired blocks, grid (8, 64)
    flash_fwd<<<dim3(8, B_ * NH_), 256, 0, stream>>>(qkv, Kpk, Vtv, qkv);

    // output projection: 2 strips of 2048 cols, fp32 out
    for (int s = 0; s < 2; s++) {
        transpose_b<float, bf16><<<dim3(64, 128, 1), tb, 0, stream>>>(
            wo + 2048 * s, R1, 4096, 4096, 1, 0, 0, 0);
        gemm256<float><<<dim3(8, 16), 512, 0, stream>>>(
            qkv, R1, R1, 1 << 30, out, QLD, 4096, 2048 * s);
    }
}

// Round 5
// 842.075 us; speedup vs baseline: 1.8566x; 1.1581x over previous
//
#include <hip/hip_runtime.h>

#define B_ 2
#define S_ 2048
#define H_ 4096
#define NH_ 32
#define NKV_ 8
#define HD_ 128
#define QST 4096   // Q/O row stride (dedicated [4096][4096] buffer)
#define KVS 2048   // K/V buffer row stride (K cols [0,1024), V cols [1024,2048))

typedef __bf16 bf16;
typedef __bf16 bf16x8 __attribute__((ext_vector_type(8)));
typedef float floatx4 __attribute__((ext_vector_type(4)));
typedef float floatx16 __attribute__((ext_vector_type(16)));
typedef unsigned int u32;

static __device__ __forceinline__ floatx4 fzero4() {
    floatx4 v; v[0] = 0.f; v[1] = 0.f; v[2] = 0.f; v[3] = 0.f; return v;
}

// async global -> LDS, 16 bytes per lane (dest linear in lane; src per-lane)
static __device__ __forceinline__ void gload16(const bf16* g, bf16* l) {
    __builtin_amdgcn_global_load_lds((const __attribute__((address_space(1))) u32*)g,
                                     (__attribute__((address_space(3))) u32*)l,
                                     16, 0, 0);
}

// ---------------------------------------------------------------------------
// fp32 -> bf16 bulk convert (hs staged once; all GEMMs then take bf16 A)
// ---------------------------------------------------------------------------
__global__ void conv_f32_bf16(const float* __restrict__ in, bf16* __restrict__ out) {
    const long long N = (long long)4096 * 4096;
    long long i = ((long long)blockIdx.x * 256 + threadIdx.x) * 8;
    const long long stride = (long long)gridDim.x * 256 * 8;
    for (; i < N; i += stride) {
        float4 a = *(const float4*)(in + i);
        float4 b = *(const float4*)(in + i + 4);
        bf16x8 h;
        h[0] = (bf16)a.x; h[1] = (bf16)a.y; h[2] = (bf16)a.z; h[3] = (bf16)a.w;
        h[4] = (bf16)b.x; h[5] = (bf16)b.y; h[6] = (bf16)b.z; h[7] = (bf16)b.w;
        *(bf16x8*)(out + i) = h;
    }
}

// ---------------------------------------------------------------------------
// 256x256-tile counted-vmcnt GEMM (round-4 verified schedule).  512 threads
// = 8 waves (2M x 4N), BK=64, K=4096, LDS 128 KiB (2 slots), T2 XOR-swizzle,
// vmcnt never 0 in-loop.  B^T split across two regions at row nsplit;
// C split across two buffers at column csplit (both 256-aligned).
// ---------------------------------------------------------------------------
template <typename TC>
__global__ __launch_bounds__(512) void gemm256(const bf16* __restrict__ A,
                                               const bf16* __restrict__ Bt0,
                                               const bf16* __restrict__ Bt1,
                                               int nsplit,
                                               TC* __restrict__ C0,
                                               TC* __restrict__ C1,
                                               int csplit,
                                               int lda, int ldC0, int ldC1) {
    __shared__ __align__(16) bf16 lds[2][2][2][8192]; // [slot][op A/B][half][128*64]

    const int tid  = threadIdx.x;
    const int wid  = tid >> 6;
    const int lane = tid & 63;
    const int quad = lane >> 4;
    const int l16  = lane & 15;
    const int wr   = wid >> 2;       // 0..1  (M)
    const int wc   = wid & 3;        // 0..3  (N)

    // XCD-aware bijective swizzle (nwg % 8 == 0 for all launches)
    const u32 nbx  = gridDim.x;
    const u32 flat = blockIdx.y * nbx + blockIdx.x;
    const u32 cpx  = (nbx * gridDim.y) >> 3;
    const u32 swz  = (flat & 7) * cpx + (flat >> 3);
    const int m0   = (int)(swz / nbx) * 256;
    const int n0t  = (int)(swz % nbx) * 256;

    const bf16* Bt = (n0t < nsplit) ? Bt0 + (size_t)n0t * 4096
                                    : Bt1 + (size_t)(n0t - nsplit) * 4096;

    floatx4 acc[8][4];
#pragma unroll
    for (int i = 0; i < 8; i++)
#pragma unroll
        for (int j = 0; j < 4; j++) acc[i][j] = fzero4();

    // stage chunk c (0..7) of the K-tile at k0 into slot s.
    // c: 0-1 = A half0, 2-3 = A half1, 4-5 = B half0, 6-7 = B half1.
    auto stageChunk = [&](int s, int k0, int c) {
        const int op   = c >> 2;
        const int half = (c >> 1) & 1;
        const int r    = (c & 1) * 64 + (tid >> 3);
        const int gs   = tid & 7;
        const int glog = gs ^ (r & 7);
        const int G    = (c & 1) * 512 + tid;
        const bf16* src = op
            ? Bt + (size_t)(half * 128 + r) * 4096 + k0 + glog * 8
            : A + (size_t)(m0 + half * 128 + r) * lda + k0 + glog * 8;
        gload16(src, &lds[s][op][half][(size_t)G * 8]);
    };

    const int NT = 4096 / 64;   // 64 K-tiles
#pragma unroll
    for (int c = 0; c < 8; c++) stageChunk(0, 0, c);
#pragma unroll
    for (int c = 0; c < 8; c++) stageChunk(1, 64, c);

    for (int g = 0; g < NT; ++g) {
        const int s = g & 1;
        if (g >= 1 && g + 1 < NT) {
            const int kn = (g + 1) * 64;
#pragma unroll
            for (int c = 0; c < 8; c++) stageChunk((g + 1) & 1, kn, c);
        }
        if (g + 1 < NT) asm volatile("s_waitcnt vmcnt(8)" ::: "memory");
        else            asm volatile("s_waitcnt vmcnt(0)" ::: "memory");
        __builtin_amdgcn_sched_barrier(0);
        __builtin_amdgcn_s_barrier();

#pragma unroll
        for (int p = 0; p < 4; p++) {
            const int qm = p >> 1, qn = p & 1;
            bf16x8 af[4][2], bfr[2][2];
#pragma unroll
            for (int i = 0; i < 4; i++) {
                const int r = (qm * 4 + i) * 16 + l16;
#pragma unroll
                for (int ks = 0; ks < 2; ks++)
                    af[i][ks] = *(const bf16x8*)&lds[s][0][wr]
                        [(size_t)r * 64 + ((ks * 4 + quad) ^ (r & 7)) * 8];
            }
#pragma unroll
            for (int j = 0; j < 2; j++) {
                const int rb = (wc & 1) * 64 + (qn * 2 + j) * 16 + l16;
#pragma unroll
                for (int ks = 0; ks < 2; ks++)
                    bfr[j][ks] = *(const bf16x8*)&lds[s][1][wc >> 1]
                        [(size_t)rb * 64 + ((ks * 4 + quad) ^ (rb & 7)) * 8];
            }
            __builtin_amdgcn_s_barrier();
            __builtin_amdgcn_s_setprio(1);
#pragma unroll
            for (int i = 0; i < 4; i++)
#pragma unroll
                for (int j = 0; j < 2; j++)
#pragma unroll
                    for (int ks = 0; ks < 2; ks++)
                        acc[qm * 4 + i][qn * 2 + j] =
                            __builtin_amdgcn_mfma_f32_16x16x32_bf16(
                                af[i][ks], bfr[j][ks],
                                acc[qm * 4 + i][qn * 2 + j], 0, 0, 0);
            __builtin_amdgcn_s_setprio(0);
            __builtin_amdgcn_s_barrier();
        }
    }

    // epilogue: D layout row = quad*4 + rr, col = l16 (m89-verified).
    // C-split is block-uniform (tiles are 256-wide, csplit 256-aligned).
    TC* Cb; int ldC, cb0;
    if (n0t < csplit) { Cb = C0; ldC = ldC0; cb0 = n0t; }
    else              { Cb = C1; ldC = ldC1; cb0 = n0t - csplit; }
#pragma unroll
    for (int fa = 0; fa < 8; fa++) {
#pragma unroll
        for (int rr = 0; rr < 4; rr++) {
            const int row = m0 + wr * 128 + fa * 16 + quad * 4 + rr;
#pragma unroll
            for (int fb = 0; fb < 4; fb++) {
                const int col = cb0 + wc * 64 + fb * 16 + l16;
                Cb[(size_t)row * ldC + col] = (TC)acc[fa][fb][rr];
            }
        }
    }
}

// ---------------------------------------------------------------------------
// Batched strided transpose + dtype convert: out[z][c][r] = in_base(z)[r][c].
// ---------------------------------------------------------------------------
template <typename TI, typename TO>
__global__ void transpose_b(const TI* __restrict__ in, TO* __restrict__ out,
                            long long irs, long long ors,
                            int zdiv, long long zs1, long long zs2,
                            long long ozs) {
    __shared__ TI t[32][33];
    const int z = blockIdx.z;
    const TI* ip = in + (long long)(z / zdiv) * zs1 + (long long)(z % zdiv) * zs2;
    TO* op = out + (long long)z * ozs;
    const int r0 = blockIdx.y * 32, c0 = blockIdx.x * 32;
    const int tx = threadIdx.x, ty = threadIdx.y;   // block (32,8)
#pragma unroll
    for (int i = 0; i < 4; i++)
        t[ty + i * 8][tx] = ip[(long long)(r0 + ty + i * 8) * irs + c0 + tx];
    __syncthreads();
#pragma unroll
    for (int i = 0; i < 4; i++)
        op[(long long)(c0 + ty + i * 8) * ors + r0 + tx] = (TO)t[tx][ty + i * 8];
}

// ---------------------------------------------------------------------------
// RoPE on q buffer [4096][4096] in place, with 1/sqrt(HD) folded in.
// ---------------------------------------------------------------------------
__global__ void rope_q(bf16* __restrict__ q, const float* __restrict__ cosb,
                       const float* __restrict__ sinb) {
    const float QSC = 0.08838834764831845f;   // 1/sqrt(128), folded into Q
    size_t idx = (size_t)blockIdx.x * 256 + threadIdx.x; // B*S*NH*64
    int dp = idx & 63;
    size_t t = idx >> 6;
    int h = (int)(t % NH_);
    size_t bs = t / NH_;                 // b*S + s
    size_t base = bs * QST + (size_t)h * HD_;
    float x1 = (float)q[base + dp];
    float x2 = (float)q[base + dp + 64];
    float c1 = cosb[bs * HD_ + dp];
    float s1 = sinb[bs * HD_ + dp];
    float c2 = cosb[bs * HD_ + dp + 64];
    float s2 = sinb[bs * HD_ + dp + 64];
    q[base + dp]      = (bf16)((x1 * c1 - x2 * s1) * QSC);
    q[base + dp + 64] = (bf16)((x2 * c2 + x1 * s2) * QSC);
}

// ---------------------------------------------------------------------------
// RoPE + repack K: kv buffer cols [0,1024) -> kout [b][kv][s][d]   (bf16)
// ---------------------------------------------------------------------------
__global__ void repack_k_rope(const bf16* __restrict__ kvb, bf16* __restrict__ kout,
                              const float* __restrict__ cosb,
                              const float* __restrict__ sinb) {
    size_t idx = (size_t)blockIdx.x * 256 + threadIdx.x; // B*S*NKV*64
    int dp = idx & 63;
    size_t t = idx >> 6;
    int kv = (int)(t % NKV_);
    size_t bs = t / NKV_;                // b*S + s
    int b = (int)(bs / S_);
    int s = (int)(bs % S_);
    size_t ibase = bs * KVS + (size_t)kv * HD_;
    float x1 = (float)kvb[ibase + dp];
    float x2 = (float)kvb[ibase + dp + 64];
    float c1 = cosb[bs * HD_ + dp];
    float s1 = sinb[bs * HD_ + dp];
    float c2 = cosb[bs * HD_ + dp + 64];
    float s2 = sinb[bs * HD_ + dp + 64];
    size_t obase = (((size_t)b * NKV_ + kv) * S_ + s) * HD_;
    kout[obase + dp]      = (bf16)(x1 * c1 - x2 * s1);
    kout[obase + dp + 64] = (bf16)(x2 * c2 + x1 * s2);
}

// ---------------------------------------------------------------------------
// Causal flash attention v3 (round-3 verified: paired blocks, double-buffered
// K/V via global_load_lds, swizzled LDS, defer-max, one barrier/iter).
// Q/O now stride QST=4096 (dedicated buffer).
// ---------------------------------------------------------------------------
__global__ __launch_bounds__(256) void flash_fwd(const bf16* __restrict__ Q,
                                                 const bf16* __restrict__ Kp,
                                                 const bf16* __restrict__ Vt,
                                                 bf16* __restrict__ O) {
    __shared__ __align__(16) bf16 smem[32768];   // 64 KiB: 2 x (Ks 8K + Vs 8K els)

    const int bh = blockIdx.y;
    const int b = bh >> 5, h = bh & 31, kv = h >> 2;   // NH=32, NH/NKV=4
    const int tid = threadIdx.x, w = tid >> 6, lane = tid & 63;
    const int l32 = lane & 31, hlf = lane >> 5;

    const bf16* Kb = Kp + (size_t)(b * NKV_ + kv) * S_ * HD_;
    const bf16* Vb = Vt + (size_t)(b * NKV_ + kv) * (size_t)HD_ * S_;
    const bf16* Qbase = Q + (size_t)b * S_ * QST + (size_t)h * HD_;
    bf16* Obase = O + (size_t)b * S_ * QST + (size_t)h * HD_;

    auto stage = [&](int kbase, bf16* KsB, bf16* VsB) {
#pragma unroll
        for (int i = 0; i < 4; i++) {
            int G = i * 256 + tid;
            int r = G >> 4, gp = G & 15;
            int gl = gp ^ (r & 15);
            gload16(Kb + (size_t)(kbase + r) * HD_ + gl * 8, KsB + (size_t)G * 8);
        }
#pragma unroll
        for (int i = 0; i < 4; i++) {
            int G = i * 256 + tid;
            int R = G >> 4, gp = G & 15;
            int g16 = gp ^ (R & 15);
            int d = R * 2 + (g16 >> 3);
            int kg = g16 & 7;
            gload16(Vb + (size_t)d * S_ + kbase + kg * 8, VsB + (size_t)G * 8);
        }
    };

    for (int pass = 0; pass < 2; ++pass) {
        const int qb = pass ? (15 - (int)blockIdx.x) : (int)blockIdx.x;
        const int q0 = qb * 128;
        const int wqmin = q0 + w * 32;
        const int wqmax = wqmin + 31;
        const int qrow = wqmin + l32;

        const bf16* Qr = Qbase + (size_t)qrow * QST;
        bf16x8 qf[8];
#pragma unroll
        for (int ks = 0; ks < 8; ks++)
            qf[ks] = *(const bf16x8*)(Qr + ks * 16 + hlf * 8);

        floatx16 ot[4];
#pragma unroll
        for (int dt = 0; dt < 4; dt++)
#pragma unroll
            for (int r = 0; r < 16; r++) ot[dt][r] = 0.f;
        float mi = -1e30f, li = 0.f;

        if (pass) __syncthreads();     // previous epilogue's LDS readers done
        stage(0, smem, smem + 8192);
        __syncthreads();               // tile 0 visible

        auto compute = [&](int kbase, const bf16* KsB, const bf16* VsB) {
            if (kbase > wqmax) return;             // wave-uniform skip
            floatx16 st[2];
#pragma unroll
            for (int n = 0; n < 2; n++)
#pragma unroll
                for (int r = 0; r < 16; r++) st[n][r] = 0.f;
#pragma unroll
            for (int ks = 0; ks < 8; ks++) {
                int phys = (ks * 2 + hlf) ^ (l32 & 15);
#pragma unroll
                for (int n = 0; n < 2; n++) {
                    bf16x8 kf = *(const bf16x8*)(KsB + (size_t)(n * 32 + l32) * 128 + phys * 8);
                    st[n] = __builtin_amdgcn_mfma_f32_32x32x16_bf16(
                        kf, qf[ks], st[n], 0, 0, 0);
                }
            }
            if (kbase + 63 > wqmin) {   // only the diagonal-intersecting tile
#pragma unroll
                for (int n = 0; n < 2; n++)
#pragma unroll
                    for (int r = 0; r < 16; r++) {
                        int key = kbase + n * 32 + (r & 3) + 8 * (r >> 2) + 4 * hlf;
                        if (key > qrow) st[n][r] = -1e30f;
                    }
            }
            float m = st[0][0];
#pragma unroll
            for (int r = 1; r < 16; r++) m = fmaxf(m, st[0][r]);
#pragma unroll
            for (int r = 0; r < 16; r++) m = fmaxf(m, st[1][r]);
            m = fmaxf(m, __shfl_xor(m, 32));
            if (!__all(m <= mi + 8.f)) {
                float mn = fmaxf(mi, m);
                float al = __expf(mi - mn);
                mi = mn;
                li *= al;
#pragma unroll
                for (int dt = 0; dt < 4; dt++)
#pragma unroll
                    for (int r = 0; r < 16; r++) ot[dt][r] *= al;
            }
            float ls = 0.f;
#pragma unroll
            for (int n = 0; n < 2; n++)
#pragma unroll
                for (int r = 0; r < 16; r++) {
                    float p = __expf(st[n][r] - mi);
                    st[n][r] = p;
                    ls += p;
                }
            ls += __shfl_xor(ls, 32);
            li += ls;

            bf16x8 pb[4];
#pragma unroll
            for (int ks2 = 0; ks2 < 4; ks2++) {
                const int n = ks2 >> 1;
                const int rb = (ks2 & 1) * 8;
                float s0 = hlf ? st[n][rb + 0] : st[n][rb + 4];
                float s1 = hlf ? st[n][rb + 1] : st[n][rb + 5];
                float s2 = hlf ? st[n][rb + 2] : st[n][rb + 6];
                float s3 = hlf ? st[n][rb + 3] : st[n][rb + 7];
                float r0 = __shfl_xor(s0, 32);
                float r1 = __shfl_xor(s1, 32);
                float r2 = __shfl_xor(s2, 32);
                float r3 = __shfl_xor(s3, 32);
                float e0, e1, e2, e3, e4, e5, e6, e7;
                if (hlf == 0) {
                    e0 = st[n][rb + 0]; e1 = st[n][rb + 1];
                    e2 = st[n][rb + 2]; e3 = st[n][rb + 3];
                    e4 = r0; e5 = r1; e6 = r2; e7 = r3;
                } else {
                    e0 = r0; e1 = r1; e2 = r2; e3 = r3;
                    e4 = st[n][rb + 4]; e5 = st[n][rb + 5];
                    e6 = st[n][rb + 6]; e7 = st[n][rb + 7];
                }
                bf16x8 t;
                t[0] = (bf16)e0; t[1] = (bf16)e1; t[2] = (bf16)e2; t[3] = (bf16)e3;
                t[4] = (bf16)e4; t[5] = (bf16)e5; t[6] = (bf16)e6; t[7] = (bf16)e7;
                pb[ks2] = t;
            }

#pragma unroll
            for (int ks2 = 0; ks2 < 4; ks2++) {
#pragma unroll
                for (int dt = 0; dt < 4; dt++) {
                    int d = dt * 32 + l32;
                    int g16 = ((d & 1) * 8 + ks2 * 2 + hlf) ^ ((d >> 1) & 15);
                    bf16x8 vf = *(const bf16x8*)(VsB + (size_t)(d >> 1) * 128 + g16 * 8);
                    ot[dt] = __builtin_amdgcn_mfma_f32_32x32x16_bf16(
                        vf, pb[ks2], ot[dt], 0, 0, 0);
                }
            }
        };

        const int nT = 2 * qb + 2;     // always even
        for (int j = 0; j < nT; j += 2) {
            stage((j + 1) * 64, smem + 16384, smem + 24576);  // -> buf1
            compute(j * 64, smem, smem + 8192);               // from buf0
            __syncthreads();                                  // drain + barrier
            if (j + 2 < nT) stage((j + 2) * 64, smem, smem + 8192);  // -> buf0
            compute((j + 1) * 64, smem + 16384, smem + 24576);       // from buf1
            __syncthreads();
        }

        {
            const float inv = 1.f / li;
            bf16* Os = smem + (size_t)w * 32 * 136;   // stride 136 els = 272 B
#pragma unroll
            for (int dt = 0; dt < 4; dt++)
#pragma unroll
                for (int r = 0; r < 16; r++) {
                    int d = dt * 32 + (r & 3) + 8 * (r >> 2) + 4 * hlf;
                    Os[l32 * 136 + d] = (bf16)(ot[dt][r] * inv);
                }
        }
        __syncthreads();
        {
#pragma unroll
            for (int i = 0; i < 8; i++) {
                int u = i * 256 + tid;
                int qa = u >> 4, gr = u & 15;
                bf16x8 v = *(const bf16x8*)(smem + (size_t)qa * 136 + gr * 8);
                *(bf16x8*)(Obase + (size_t)(q0 + qa) * QST + gr * 8) = v;
            }
        }
    }
}

// ---------------------------------------------------------------------------
extern "C" void kernel_launch(void* const* d_in, const int* in_sizes, int n_in,
                              void* d_out, int out_size, void* d_ws, size_t ws_size,
                              hipStream_t stream) {
    const float* hs   = (const float*)d_in[0];
    const float* cosb = (const float*)d_in[1];
    const float* sinb = (const float*)d_in[2];
    const float* wq   = (const float*)d_in[3];
    const float* wk   = (const float*)d_in[4];
    const float* wv   = (const float*)d_in[5];
    const float* wo   = (const float*)d_in[6];
    float* out = (float*)d_out;
    (void)in_sizes; (void)n_in; (void)out_size;

    // 72 MiB workspace (proven available in earlier sessions)
    const size_t NEED = (size_t)72 * 1024 * 1024;
    if (ws_size < NEED) return;

    char* ws = (char*)d_ws;
    bf16* qbuf = (bf16*)ws;                                  // [0,32M): Q [4096][4096]
    bf16* kvb  = (bf16*)(ws + (size_t)32 * 1024 * 1024);     // [32,48M): KV [4096][2048]
    bf16* R1   = (bf16*)(ws + (size_t)48 * 1024 * 1024);     // [48,72M): 24 MiB
    bf16* woHi = kvb;                                        // [32,40M): wo^T rows hi (after KV dead)

    // d_out doubles as scratch until the WO GEMM writes it:
    bf16* hsb  = (bf16*)d_out;                               // [0,32M): hs in bf16
    bf16* BtHi = (bf16*)((char*)d_out + (size_t)32 * 1024 * 1024); // [32,56M)

    dim3 tb(32, 8, 1);

    conv_f32_bf16<<<2048, 256, 0, stream>>>(hs, hsb);

    // fused QKV weight^T: rows [0,3072) -> R1 (wq cols 0..3071);
    // rows [3072,6144) -> BtHi (wq cols 3072..4095 ++ wk ++ wv)
    transpose_b<float, bf16><<<dim3(96, 128, 1), tb, 0, stream>>>(
        wq, R1, 4096, 4096, 1, 0, 0, 0);
    transpose_b<float, bf16><<<dim3(32, 128, 1), tb, 0, stream>>>(
        wq + 3072, BtHi, 4096, 4096, 1, 0, 0, 0);
    transpose_b<float, bf16><<<dim3(32, 128, 1), tb, 0, stream>>>(
        wk, BtHi + (size_t)1024 * 4096, 1024, 4096, 1, 0, 0, 0);
    transpose_b<float, bf16><<<dim3(32, 128, 1), tb, 0, stream>>>(
        wv, BtHi + (size_t)2048 * 4096, 1024, 4096, 1, 0, 0, 0);

    // QKV projection: ONE 384-block launch, N=6144; C split at col 4096:
    // Q -> qbuf (ldC 4096), K/V -> kvb (ldC 2048)
    gemm256<bf16><<<dim3(24, 16), 512, 0, stream>>>(
        hsb, R1, BtHi, 3072, qbuf, kvb, 4096, 4096, QST, KVS);

    // rope q in place (scale folded); repack K (rope) and transpose V
    rope_q<<<(B_ * S_ * NH_ * 64) / 256, 256, 0, stream>>>(qbuf, cosb, sinb);
    bf16* Kpk = R1;                                          // 8 MiB (R1 dead post-GEMM)
    bf16* Vtv = R1 + (size_t)B_ * NKV_ * S_ * HD_;           // 8 MiB
    repack_k_rope<<<(B_ * S_ * NKV_ * 64) / 256, 256, 0, stream>>>(
        kvb, Kpk, cosb, sinb);
    // V: kvb cols [1024,2048) [b][s][kv][d] -> [b*kv][d][s]
    transpose_b<bf16, bf16><<<dim3(HD_ / 32, S_ / 32, B_ * NKV_), tb, 0, stream>>>(
        kvb + 1024, Vtv, KVS, S_,
        NKV_, (long long)S_ * KVS, HD_, (long long)HD_ * S_);

    // attention v3: paired blocks, grid (8, 64), in place over qbuf
    flash_fwd<<<dim3(8, B_ * NH_), 256, 0, stream>>>(qbuf, Kpk, Vtv, qbuf);

    // WO projection: ONE 256-block launch (16x16 = exactly 1 block/CU).
    // wo^T rows [0,3072) -> R1 (Kpk/Vtv dead after flash);
    // wo^T rows [3072,4096) -> woHi (kvb region, dead after repack/transpose)
    transpose_b<float, bf16><<<dim3(96, 128, 1), tb, 0, stream>>>(
        wo, R1, 4096, 4096, 1, 0, 0, 0);
    transpose_b<float, bf16><<<dim3(32, 128, 1), tb, 0, stream>>>(
        wo + 3072, woHi, 4096, 4096, 1, 0, 0, 0);
    gemm256<float><<<dim3(16, 16), 512, 0, stream>>>(
        qbuf, R1, woHi, 3072, out, out, 1 << 30, QST, 4096, 4096);
}

// Round 6
// 795.537 us; speedup vs baseline: 1.9652x; 1.0585x over previous
//
#include <hip/hip_runtime.h>

#define B_ 2
#define S_ 2048
#define H_ 4096
#define NH_ 32
#define NKV_ 8
#define HD_ 128
#define QST 4096   // Q/O row stride (dedicated [4096][4096] buffer)
#define KVS 2048   // K/V buffer row stride (K cols [0,1024), V cols [1024,2048))

typedef __bf16 bf16;
typedef __bf16 bf16x8 __attribute__((ext_vector_type(8)));
typedef float floatx4 __attribute__((ext_vector_type(4)));
typedef float floatx16 __attribute__((ext_vector_type(16)));
typedef unsigned int u32;

// async global -> LDS, 16 bytes per lane (dest linear in lane; src per-lane)
static __device__ __forceinline__ void gload16(const bf16* g, bf16* l) {
    __builtin_amdgcn_global_load_lds((const __attribute__((address_space(1))) u32*)g,
                                     (__attribute__((address_space(3))) u32*)l,
                                     16, 0, 0);
}

// ---------------------------------------------------------------------------
// fp32 -> bf16 bulk convert (hs staged once; all GEMMs then take bf16 A)
// ---------------------------------------------------------------------------
__global__ void conv_f32_bf16(const float* __restrict__ in, bf16* __restrict__ out) {
    const long long N = (long long)4096 * 4096;
    long long i = ((long long)blockIdx.x * 256 + threadIdx.x) * 8;
    const long long stride = (long long)gridDim.x * 256 * 8;
    for (; i < N; i += stride) {
        float4 a = *(const float4*)(in + i);
        float4 b = *(const float4*)(in + i + 4);
        bf16x8 h;
        h[0] = (bf16)a.x; h[1] = (bf16)a.y; h[2] = (bf16)a.z; h[3] = (bf16)a.w;
        h[4] = (bf16)b.x; h[5] = (bf16)b.y; h[6] = (bf16)b.z; h[7] = (bf16)b.w;
        *(bf16x8*)(out + i) = h;
    }
}

// ---------------------------------------------------------------------------
// 256x256-tile counted-vmcnt GEMM, now on mfma_32x32x16 (2x FLOP per LDS
// byte: reads/tile/wave 48 -> 24 b128).  LDS layout: 2-row 256B super-rows
// with ^(R&15) granule swizzle (flash's verified V pattern) -> 8 words/bank,
// conflict-free.  Schedule (slots, vmcnt(8), raw barriers, setprio) is the
// round-4/5 verified skeleton, unchanged.
// ---------------------------------------------------------------------------
template <typename TC>
__global__ __launch_bounds__(512) void gemm256(const bf16* __restrict__ A,
                                               const bf16* __restrict__ Bt0,
                                               const bf16* __restrict__ Bt1,
                                               int nsplit,
                                               TC* __restrict__ C0,
                                               TC* __restrict__ C1,
                                               int csplit,
                                               int lda, int ldC0, int ldC1) {
    __shared__ __align__(16) bf16 lds[2][2][2][8192]; // [slot][op][half][64 srows x 128]

    const int tid  = threadIdx.x;
    const int wid  = tid >> 6;
    const int lane = tid & 63;
    const int l32  = lane & 31;
    const int hlf  = lane >> 5;
    const int wr   = wid >> 2;       // 0..1  (M)
    const int wc   = wid & 3;        // 0..3  (N)

    // XCD-aware bijective swizzle (nwg % 8 == 0 for all launches)
    const u32 nbx  = gridDim.x;
    const u32 flat = blockIdx.y * nbx + blockIdx.x;
    const u32 cpx  = (nbx * gridDim.y) >> 3;
    const u32 swz  = (flat & 7) * cpx + (flat >> 3);
    const int m0   = (int)(swz / nbx) * 256;
    const int n0t  = (int)(swz % nbx) * 256;

    const bf16* Bt = (n0t < nsplit) ? Bt0 + (size_t)n0t * 4096
                                    : Bt1 + (size_t)(n0t - nsplit) * 4096;

    floatx16 acc[4][2];
#pragma unroll
    for (int i = 0; i < 4; i++)
#pragma unroll
        for (int j = 0; j < 2; j++)
#pragma unroll
            for (int r = 0; r < 16; r++) acc[i][j][r] = 0.f;

    // stage chunk c (0..7) of the K-tile at k0 into slot s.
    // c: 0-1 = A half0, 2-3 = A half1, 4-5 = B half0, 6-7 = B half1.
    // Super-row layout: LDS dest linear; logical (row, k-granule) decoded by
    // g16 = slot ^ (R&15): row = 2R + (g16>>3), kg = g16&7.
    auto stageChunk = [&](int s, int k0, int c) {
        const int op   = c >> 2;
        const int half = (c >> 1) & 1;
        const int G    = (c & 1) * 512 + tid;   // granule 0..1023 in half-array
        const int R    = G >> 4, gp = G & 15;
        const int g16  = gp ^ (R & 15);
        const int rl   = R * 2 + (g16 >> 3);
        const int kg   = g16 & 7;
        const int row  = half * 128 + rl;
        const bf16* src = op
            ? Bt + (size_t)row * 4096 + k0 + kg * 8
            : A + (size_t)(m0 + row) * lda + k0 + kg * 8;
        gload16(src, &lds[s][op][half][(size_t)G * 8]);
    };

    const int NT = 4096 / 64;   // 64 K-tiles
#pragma unroll
    for (int c = 0; c < 8; c++) stageChunk(0, 0, c);
#pragma unroll
    for (int c = 0; c < 8; c++) stageChunk(1, 64, c);

    for (int g = 0; g < NT; ++g) {
        const int s = g & 1;
        if (g >= 1 && g + 1 < NT) {
            const int kn = (g + 1) * 64;
#pragma unroll
            for (int c = 0; c < 8; c++) stageChunk((g + 1) & 1, kn, c);
        }
        if (g + 1 < NT) asm volatile("s_waitcnt vmcnt(8)" ::: "memory");
        else            asm volatile("s_waitcnt vmcnt(0)" ::: "memory");
        __builtin_amdgcn_sched_barrier(0);
        __builtin_amdgcn_s_barrier();

        // 4 phases = 4 K-steps of 16; per phase: 6 ds_read_b128 + 8 MFMA 32x32
#pragma unroll
        for (int p = 0; p < 4; p++) {
            bf16x8 af[4], bfv[2];
#pragma unroll
            for (int fa = 0; fa < 4; fa++) {
                const int r = wr * 128 + fa * 32 + l32;
                const int half = r >> 7, rl = r & 127, R = rl >> 1;
                const int slot = (((rl & 1) << 3) | (p * 2 + hlf)) ^ (R & 15);
                af[fa] = *(const bf16x8*)&lds[s][0][half][(size_t)R * 128 + slot * 8];
            }
#pragma unroll
            for (int fb = 0; fb < 2; fb++) {
                const int r = wc * 64 + fb * 32 + l32;
                const int half = r >> 7, rl = r & 127, R = rl >> 1;
                const int slot = (((rl & 1) << 3) | (p * 2 + hlf)) ^ (R & 15);
                bfv[fb] = *(const bf16x8*)&lds[s][1][half][(size_t)R * 128 + slot * 8];
            }
            __builtin_amdgcn_s_barrier();
            __builtin_amdgcn_s_setprio(1);
#pragma unroll
            for (int fa = 0; fa < 4; fa++)
#pragma unroll
                for (int fb = 0; fb < 2; fb++)
                    acc[fa][fb] = __builtin_amdgcn_mfma_f32_32x32x16_bf16(
                        af[fa], bfv[fb], acc[fa][fb], 0, 0, 0);
            __builtin_amdgcn_s_setprio(0);
            __builtin_amdgcn_s_barrier();
        }
    }

    // epilogue: 32x32 D layout col = l32, row = (r&3) + 8*(r>>2) + 4*hlf
    TC* Cb; int ldC, cb0;
    if (n0t < csplit) { Cb = C0; ldC = ldC0; cb0 = n0t; }
    else              { Cb = C1; ldC = ldC1; cb0 = n0t - csplit; }
#pragma unroll
    for (int fa = 0; fa < 4; fa++)
#pragma unroll
        for (int fb = 0; fb < 2; fb++) {
            const int col = cb0 + wc * 64 + fb * 32 + l32;
#pragma unroll
            for (int r = 0; r < 16; r++) {
                const int row = m0 + wr * 128 + fa * 32 + (r & 3) + 8 * (r >> 2) + 4 * hlf;
                Cb[(size_t)row * ldC + col] = (TC)acc[fa][fb][r];
            }
        }
}

// ---------------------------------------------------------------------------
// Batched strided transpose + dtype convert: out[z][c][r] = in_base(z)[r][c].
// ---------------------------------------------------------------------------
template <typename TI, typename TO>
__global__ void transpose_b(const TI* __restrict__ in, TO* __restrict__ out,
                            long long irs, long long ors,
                            int zdiv, long long zs1, long long zs2,
                            long long ozs) {
    __shared__ TI t[32][33];
    const int z = blockIdx.z;
    const TI* ip = in + (long long)(z / zdiv) * zs1 + (long long)(z % zdiv) * zs2;
    TO* op = out + (long long)z * ozs;
    const int r0 = blockIdx.y * 32, c0 = blockIdx.x * 32;
    const int tx = threadIdx.x, ty = threadIdx.y;   // block (32,8)
#pragma unroll
    for (int i = 0; i < 4; i++)
        t[ty + i * 8][tx] = ip[(long long)(r0 + ty + i * 8) * irs + c0 + tx];
    __syncthreads();
#pragma unroll
    for (int i = 0; i < 4; i++)
        op[(long long)(c0 + ty + i * 8) * ors + r0 + tx] = (TO)t[tx][ty + i * 8];
}

// ---------------------------------------------------------------------------
// RoPE on q buffer [4096][4096] in place, with 1/sqrt(HD) folded in.
// ---------------------------------------------------------------------------
__global__ void rope_q(bf16* __restrict__ q, const float* __restrict__ cosb,
                       const float* __restrict__ sinb) {
    const float QSC = 0.08838834764831845f;   // 1/sqrt(128), folded into Q
    size_t idx = (size_t)blockIdx.x * 256 + threadIdx.x; // B*S*NH*64
    int dp = idx & 63;
    size_t t = idx >> 6;
    int h = (int)(t % NH_);
    size_t bs = t / NH_;                 // b*S + s
    size_t base = bs * QST + (size_t)h * HD_;
    float x1 = (float)q[base + dp];
    float x2 = (float)q[base + dp + 64];
    float c1 = cosb[bs * HD_ + dp];
    float s1 = sinb[bs * HD_ + dp];
    float c2 = cosb[bs * HD_ + dp + 64];
    float s2 = sinb[bs * HD_ + dp + 64];
    q[base + dp]      = (bf16)((x1 * c1 - x2 * s1) * QSC);
    q[base + dp + 64] = (bf16)((x2 * c2 + x1 * s2) * QSC);
}

// ---------------------------------------------------------------------------
// RoPE + repack K: kv buffer cols [0,1024) -> kout [b][kv][s][d]   (bf16)
// ---------------------------------------------------------------------------
__global__ void repack_k_rope(const bf16* __restrict__ kvb, bf16* __restrict__ kout,
                              const float* __restrict__ cosb,
                              const float* __restrict__ sinb) {
    size_t idx = (size_t)blockIdx.x * 256 + threadIdx.x; // B*S*NKV*64
    int dp = idx & 63;
    size_t t = idx >> 6;
    int kv = (int)(t % NKV_);
    size_t bs = t / NKV_;                // b*S + s
    int b = (int)(bs / S_);
    int s = (int)(bs % S_);
    size_t ibase = bs * KVS + (size_t)kv * HD_;
    float x1 = (float)kvb[ibase + dp];
    float x2 = (float)kvb[ibase + dp + 64];
    float c1 = cosb[bs * HD_ + dp];
    float s1 = sinb[bs * HD_ + dp];
    float c2 = cosb[bs * HD_ + dp + 64];
    float s2 = sinb[bs * HD_ + dp + 64];
    size_t obase = (((size_t)b * NKV_ + kv) * S_ + s) * HD_;
    kout[obase + dp]      = (bf16)(x1 * c1 - x2 * s1);
    kout[obase + dp + 64] = (bf16)(x2 * c2 + x1 * s2);
}

// ---------------------------------------------------------------------------
// Causal flash attention v4: round-3 compute internals (verified), loop
// skeleton replaced with raw-barrier counted-vmcnt schedule (gemm256's
// verified pattern).  __syncthreads' implicit vmcnt(0) was draining the
// prefetch every iteration -> now loads stay in flight across barriers.
// ---------------------------------------------------------------------------
__global__ __launch_bounds__(256) void flash_fwd(const bf16* __restrict__ Q,
                                                 const bf16* __restrict__ Kp,
                                                 const bf16* __restrict__ Vt,
                                                 bf16* __restrict__ O) {
    __shared__ __align__(16) bf16 smem[32768];   // 64 KiB: 2 x (Ks 8K + Vs 8K els)

    const int bh = blockIdx.y;
    const int b = bh >> 5, h = bh & 31, kv = h >> 2;   // NH=32, NH/NKV=4
    const int tid = threadIdx.x, w = tid >> 6, lane = tid & 63;
    const int l32 = lane & 31, hlf = lane >> 5;

    const bf16* Kb = Kp + (size_t)(b * NKV_ + kv) * S_ * HD_;
    const bf16* Vb = Vt + (size_t)(b * NKV_ + kv) * (size_t)HD_ * S_;
    const bf16* Qbase = Q + (size_t)b * S_ * QST + (size_t)h * HD_;
    bf16* Obase = O + (size_t)b * S_ * QST + (size_t)h * HD_;

    auto stage = [&](int kbase, bf16* KsB, bf16* VsB) {
#pragma unroll
        for (int i = 0; i < 4; i++) {
            int G = i * 256 + tid;
            int r = G >> 4, gp = G & 15;
            int gl = gp ^ (r & 15);
            gload16(Kb + (size_t)(kbase + r) * HD_ + gl * 8, KsB + (size_t)G * 8);
        }
#pragma unroll
        for (int i = 0; i < 4; i++) {
            int G = i * 256 + tid;
            int R = G >> 4, gp = G & 15;
            int g16 = gp ^ (R & 15);
            int d = R * 2 + (g16 >> 3);
            int kg = g16 & 7;
            gload16(Vb + (size_t)d * S_ + kbase + kg * 8, VsB + (size_t)G * 8);
        }
    };

    for (int pass = 0; pass < 2; ++pass) {
        const int qb = pass ? (15 - (int)blockIdx.x) : (int)blockIdx.x;
        const int q0 = qb * 128;
        const int wqmin = q0 + w * 32;
        const int wqmax = wqmin + 31;
        const int qrow = wqmin + l32;

        const bf16* Qr = Qbase + (size_t)qrow * QST;
        bf16x8 qf[8];
#pragma unroll
        for (int ks = 0; ks < 8; ks++)
            qf[ks] = *(const bf16x8*)(Qr + ks * 16 + hlf * 8);

        floatx16 ot[4];
#pragma unroll
        for (int dt = 0; dt < 4; dt++)
#pragma unroll
            for (int r = 0; r < 16; r++) ot[dt][r] = 0.f;
        float mi = -1e30f, li = 0.f;

        auto compute = [&](int kbase, const bf16* KsB, const bf16* VsB) {
            if (kbase > wqmax) return;             // wave-uniform skip
            floatx16 st[2];
#pragma unroll
            for (int n = 0; n < 2; n++)
#pragma unroll
                for (int r = 0; r < 16; r++) st[n][r] = 0.f;
            __builtin_amdgcn_s_setprio(1);
#pragma unroll
            for (int ks = 0; ks < 8; ks++) {
                int phys = (ks * 2 + hlf) ^ (l32 & 15);
#pragma unroll
                for (int n = 0; n < 2; n++) {
                    bf16x8 kf = *(const bf16x8*)(KsB + (size_t)(n * 32 + l32) * 128 + phys * 8);
                    st[n] = __builtin_amdgcn_mfma_f32_32x32x16_bf16(
                        kf, qf[ks], st[n], 0, 0, 0);
                }
            }
            __builtin_amdgcn_s_setprio(0);
            if (kbase + 63 > wqmin) {   // only the diagonal-intersecting tile
#pragma unroll
                for (int n = 0; n < 2; n++)
#pragma unroll
                    for (int r = 0; r < 16; r++) {
                        int key = kbase + n * 32 + (r & 3) + 8 * (r >> 2) + 4 * hlf;
                        if (key > qrow) st[n][r] = -1e30f;
                    }
            }
            float m = st[0][0];
#pragma unroll
            for (int r = 1; r < 16; r++) m = fmaxf(m, st[0][r]);
#pragma unroll
            for (int r = 0; r < 16; r++) m = fmaxf(m, st[1][r]);
            m = fmaxf(m, __shfl_xor(m, 32));
            if (!__all(m <= mi + 8.f)) {
                float mn = fmaxf(mi, m);
                float al = __expf(mi - mn);
                mi = mn;
                li *= al;
#pragma unroll
                for (int dt = 0; dt < 4; dt++)
#pragma unroll
                    for (int r = 0; r < 16; r++) ot[dt][r] *= al;
            }
            float ls = 0.f;
#pragma unroll
            for (int n = 0; n < 2; n++)
#pragma unroll
                for (int r = 0; r < 16; r++) {
                    float p = __expf(st[n][r] - mi);
                    st[n][r] = p;
                    ls += p;
                }
            ls += __shfl_xor(ls, 32);
            li += ls;

            bf16x8 pb[4];
#pragma unroll
            for (int ks2 = 0; ks2 < 4; ks2++) {
                const int n = ks2 >> 1;
                const int rb = (ks2 & 1) * 8;
                float s0 = hlf ? st[n][rb + 0] : st[n][rb + 4];
                float s1 = hlf ? st[n][rb + 1] : st[n][rb + 5];
                float s2 = hlf ? st[n][rb + 2] : st[n][rb + 6];
                float s3 = hlf ? st[n][rb + 3] : st[n][rb + 7];
                float r0 = __shfl_xor(s0, 32);
                float r1 = __shfl_xor(s1, 32);
                float r2 = __shfl_xor(s2, 32);
                float r3 = __shfl_xor(s3, 32);
                float e0, e1, e2, e3, e4, e5, e6, e7;
                if (hlf == 0) {
                    e0 = st[n][rb + 0]; e1 = st[n][rb + 1];
                    e2 = st[n][rb + 2]; e3 = st[n][rb + 3];
                    e4 = r0; e5 = r1; e6 = r2; e7 = r3;
                } else {
                    e0 = r0; e1 = r1; e2 = r2; e3 = r3;
                    e4 = st[n][rb + 4]; e5 = st[n][rb + 5];
                    e6 = st[n][rb + 6]; e7 = st[n][rb + 7];
                }
                bf16x8 t;
                t[0] = (bf16)e0; t[1] = (bf16)e1; t[2] = (bf16)e2; t[3] = (bf16)e3;
                t[4] = (bf16)e4; t[5] = (bf16)e5; t[6] = (bf16)e6; t[7] = (bf16)e7;
                pb[ks2] = t;
            }

            __builtin_amdgcn_s_setprio(1);
#pragma unroll
            for (int ks2 = 0; ks2 < 4; ks2++) {
#pragma unroll
                for (int dt = 0; dt < 4; dt++) {
                    int d = dt * 32 + l32;
                    int g16 = ((d & 1) * 8 + ks2 * 2 + hlf) ^ ((d >> 1) & 15);
                    bf16x8 vf = *(const bf16x8*)(VsB + (size_t)(d >> 1) * 128 + g16 * 8);
                    ot[dt] = __builtin_amdgcn_mfma_f32_32x32x16_bf16(
                        vf, pb[ks2], ot[dt], 0, 0, 0);
                }
            }
            __builtin_amdgcn_s_setprio(0);
        };

        if (pass) __syncthreads();     // previous epilogue's LDS readers done
        stage(0, smem, smem + 8192);

        const int nT = 2 * qb + 2;
        for (int j = 0; j < nT; ++j) {
            bf16* cur = smem + (size_t)(j & 1) * 16384;
            if (j + 1 < nT) {
                bf16* nxt = smem + (size_t)((j + 1) & 1) * 16384;
                stage((j + 1) * 64, nxt, nxt + 8192);
                asm volatile("s_waitcnt vmcnt(8)" ::: "memory");
            } else {
                asm volatile("s_waitcnt vmcnt(0)" ::: "memory");
            }
            __builtin_amdgcn_sched_barrier(0);
            __builtin_amdgcn_s_barrier();
            compute(j * 64, cur, cur + 8192);
            asm volatile("s_waitcnt lgkmcnt(0)" ::: "memory");
            __builtin_amdgcn_sched_barrier(0);
            __builtin_amdgcn_s_barrier();
        }

        {
            const float inv = 1.f / li;
            bf16* Os = smem + (size_t)w * 32 * 136;   // stride 136 els = 272 B
#pragma unroll
            for (int dt = 0; dt < 4; dt++)
#pragma unroll
                for (int r = 0; r < 16; r++) {
                    int d = dt * 32 + (r & 3) + 8 * (r >> 2) + 4 * hlf;
                    Os[l32 * 136 + d] = (bf16)(ot[dt][r] * inv);
                }
        }
        __syncthreads();
        {
#pragma unroll
            for (int i = 0; i < 8; i++) {
                int u = i * 256 + tid;
                int qa = u >> 4, gr = u & 15;
                bf16x8 v = *(const bf16x8*)(smem + (size_t)qa * 136 + gr * 8);
                *(bf16x8*)(Obase + (size_t)(q0 + qa) * QST + gr * 8) = v;
            }
        }
    }
}

// ---------------------------------------------------------------------------
extern "C" void kernel_launch(void* const* d_in, const int* in_sizes, int n_in,
                              void* d_out, int out_size, void* d_ws, size_t ws_size,
                              hipStream_t stream) {
    const float* hs   = (const float*)d_in[0];
    const float* cosb = (const float*)d_in[1];
    const float* sinb = (const float*)d_in[2];
    const float* wq   = (const float*)d_in[3];
    const float* wk   = (const float*)d_in[4];
    const float* wv   = (const float*)d_in[5];
    const float* wo   = (const float*)d_in[6];
    float* out = (float*)d_out;
    (void)in_sizes; (void)n_in; (void)out_size;

    // 72 MiB workspace (proven available in earlier sessions)
    const size_t NEED = (size_t)72 * 1024 * 1024;
    if (ws_size < NEED) return;

    char* ws = (char*)d_ws;
    bf16* qbuf = (bf16*)ws;                                  // [0,32M): Q [4096][4096]
    bf16* kvb  = (bf16*)(ws + (size_t)32 * 1024 * 1024);     // [32,48M): KV [4096][2048]
    bf16* R1   = (bf16*)(ws + (size_t)48 * 1024 * 1024);     // [48,72M): 24 MiB
    bf16* woHi = kvb;                                        // [32,40M): wo^T hi (after KV dead)

    // d_out doubles as scratch until the WO GEMM writes it:
    bf16* hsb  = (bf16*)d_out;                               // [0,32M): hs in bf16
    bf16* BtHi = (bf16*)((char*)d_out + (size_t)32 * 1024 * 1024); // [32,56M)

    dim3 tb(32, 8, 1);

    conv_f32_bf16<<<2048, 256, 0, stream>>>(hs, hsb);

    // fused QKV weight^T: rows [0,3072) -> R1 (wq cols 0..3071);
    // rows [3072,6144) -> BtHi (wq cols 3072..4095 ++ wk ++ wv)
    transpose_b<float, bf16><<<dim3(96, 128, 1), tb, 0, stream>>>(
        wq, R1, 4096, 4096, 1, 0, 0, 0);
    transpose_b<float, bf16><<<dim3(32, 128, 1), tb, 0, stream>>>(
        wq + 3072, BtHi, 4096, 4096, 1, 0, 0, 0);
    transpose_b<float, bf16><<<dim3(32, 128, 1), tb, 0, stream>>>(
        wk, BtHi + (size_t)1024 * 4096, 1024, 4096, 1, 0, 0, 0);
    transpose_b<float, bf16><<<dim3(32, 128, 1), tb, 0, stream>>>(
        wv, BtHi + (size_t)2048 * 4096, 1024, 4096, 1, 0, 0, 0);

    // QKV projection: ONE 384-block launch, N=6144; C split at col 4096:
    // Q -> qbuf (ldC 4096), K/V -> kvb (ldC 2048)
    gemm256<bf16><<<dim3(24, 16), 512, 0, stream>>>(
        hsb, R1, BtHi, 3072, qbuf, kvb, 4096, 4096, QST, KVS);

    // rope q in place (scale folded); repack K (rope) and transpose V
    rope_q<<<(B_ * S_ * NH_ * 64) / 256, 256, 0, stream>>>(qbuf, cosb, sinb);
    bf16* Kpk = R1;                                          // 8 MiB (R1 dead post-GEMM)
    bf16* Vtv = R1 + (size_t)B_ * NKV_ * S_ * HD_;           // 8 MiB
    repack_k_rope<<<(B_ * S_ * NKV_ * 64) / 256, 256, 0, stream>>>(
        kvb, Kpk, cosb, sinb);
    // V: kvb cols [1024,2048) [b][s][kv][d] -> [b*kv][d][s]
    transpose_b<bf16, bf16><<<dim3(HD_ / 32, S_ / 32, B_ * NKV_), tb, 0, stream>>>(
        kvb + 1024, Vtv, KVS, S_,
        NKV_, (long long)S_ * KVS, HD_, (long long)HD_ * S_);

    // attention v4: paired blocks, grid (8, 64), in place over qbuf
    flash_fwd<<<dim3(8, B_ * NH_), 256, 0, stream>>>(qbuf, Kpk, Vtv, qbuf);

    // WO projection: ONE 256-block launch (16x16 = exactly 1 block/CU).
    transpose_b<float, bf16><<<dim3(96, 128, 1), tb, 0, stream>>>(
        wo, R1, 4096, 4096, 1, 0, 0, 0);
    transpose_b<float, bf16><<<dim3(32, 128, 1), tb, 0, stream>>>(
        wo + 3072, woHi, 4096, 4096, 1, 0, 0, 0);
    gemm256<float><<<dim3(16, 16), 512, 0, stream>>>(
        qbuf, R1, woHi, 3072, out, out, 1 << 30, QST, 4096, 4096);
}